// Round 1
// baseline (503.932 us; speedup 1.0000x reference)
//
#include <hip/hip_runtime.h>
#include <stdint.h>

// ---------------- bf16-as-short helpers ----------------
typedef short s16;
typedef __attribute__((ext_vector_type(8))) short short8;  // MFMA A/B frag: 8 bf16 (4 VGPRs)
typedef __attribute__((ext_vector_type(4))) float f32x4;   // MFMA C/D frag

__device__ __forceinline__ s16 f2bf(float f) {
  union { float f; uint32_t u; } v; v.f = f;
  uint32_t u = v.u;
  uint32_t r = (u + 0x7fffu + ((u >> 16) & 1u)) >> 16;  // round-to-nearest-even
  return (s16)(uint16_t)r;
}

#define GLOBAL_AS __attribute__((address_space(1)))
#define LDS_AS    __attribute__((address_space(3)))
__device__ __forceinline__ void gload_lds16(const void* g, void* l) {
  __builtin_amdgcn_global_load_lds((const GLOBAL_AS uint32_t*)g, (LDS_AS uint32_t*)l, 16, 0, 0);
}

// ---------------- GEMM: C(MxN) = A(MxK,row-major) @ B, with B supplied as BT(NxK,row-major)
// epilogue: v = acc * (colscale?colscale[col]:1) + (addend?addend[idx]:0)
//           C[idx]=v; optional bf16 writes plain (obf_n) and transposed (obf_t, [N][M]).
#define BM 128
#define BN 128
#define BK 32

__global__ void __launch_bounds__(256)
gemm_bt(const s16* __restrict__ A, const s16* __restrict__ BT,
        float* C, int M, int N, int K,
        const float* __restrict__ colscale,
        const float* addend,            // may alias C (in-place); no restrict
        s16* __restrict__ obf_n, s16* __restrict__ obf_t)
{
  __shared__ alignas(16) s16 lta[BM * BK];  // [m][k]
  __shared__ alignas(16) s16 ltb[BN * BK];  // [n][k]
  const int tid  = threadIdx.x;
  const int lane = tid & 63;
  const int wave = tid >> 6;
  const int wr = wave >> 1, wc = wave & 1;
  const int bm0 = blockIdx.y * BM;
  const int bn0 = blockIdx.x * BN;

  f32x4 acc[4][4];
  #pragma unroll
  for (int i = 0; i < 4; ++i)
    #pragma unroll
    for (int j = 0; j < 4; ++j)
      #pragma unroll
      for (int r = 0; r < 4; ++r) acc[i][j][r] = 0.0f;

  const int ca0  = wave * 2;        // 2 chunks of A and of B per wave
  const int srow = lane >> 2;       // 0..15 row within 16-row chunk
  const int ske  = (lane & 3) * 8;  // k element offset (8 bf16 = 16B per lane)

  for (int kt = 0; kt < K; kt += BK) {
    #pragma unroll
    for (int c = 0; c < 2; ++c) {
      const int ch = ca0 + c;
      gload_lds16(A + (size_t)(bm0 + ch * 16 + srow) * K + kt + ske, &lta[ch * 512]);
    }
    #pragma unroll
    for (int c = 0; c < 2; ++c) {
      const int ch = ca0 + c;
      gload_lds16(BT + (size_t)(bn0 + ch * 16 + srow) * K + kt + ske, &ltb[ch * 512]);
    }
    __syncthreads();   // drains vmcnt (global_load_lds) before reads

    const int fr = lane & 15;
    const int k8 = (lane >> 4) * 8;
    short8 af[4], bfr[4];
    #pragma unroll
    for (int i = 0; i < 4; ++i)
      af[i] = *(const short8*)&lta[(wr * 64 + i * 16 + fr) * BK + k8];
    #pragma unroll
    for (int j = 0; j < 4; ++j)
      bfr[j] = *(const short8*)&ltb[(wc * 64 + j * 16 + fr) * BK + k8];
    #pragma unroll
    for (int i = 0; i < 4; ++i)
      #pragma unroll
      for (int j = 0; j < 4; ++j)
        acc[i][j] = __builtin_amdgcn_mfma_f32_16x16x32_bf16(af[i], bfr[j], acc[i][j], 0, 0, 0);
    __syncthreads();   // compute done before next tile overwrites LDS
  }

  // epilogue — C/D layout (m89): col = lane&15, row = (lane>>4)*4 + reg
  const int r0 = (lane >> 4) * 4;
  const int cl = lane & 15;
  #pragma unroll
  for (int i = 0; i < 4; ++i) {
    const int gm = bm0 + wr * 64 + i * 16 + r0;
    #pragma unroll
    for (int j = 0; j < 4; ++j) {
      const int gn = bn0 + wc * 64 + j * 16 + cl;
      const float cs = colscale ? colscale[gn] : 1.0f;
      #pragma unroll
      for (int r = 0; r < 4; ++r) {
        const size_t idx = (size_t)(gm + r) * N + gn;
        float v = acc[i][j][r] * cs;
        if (addend) v += addend[idx];
        C[idx] = v;
        if (obf_n) obf_n[idx] = f2bf(v);
        if (obf_t) obf_t[(size_t)gn * M + (gm + r)] = f2bf(v);
      }
    }
  }
}

// ---------------- fp32 -> bf16 convert, plain and/or transposed (64x64 tiles) ----
__global__ void __launch_bounds__(256)
k_cvt_dual(const float* __restrict__ in, s16* __restrict__ outp, s16* __restrict__ outt,
           int R, int C)
{
  __shared__ float t[64][65];
  const int bx = blockIdx.x * 64, by = blockIdx.y * 64;
  const int tx = threadIdx.x & 63, ty = threadIdx.x >> 6;
  #pragma unroll
  for (int rr = 0; rr < 16; ++rr) {
    const int r = ty * 16 + rr;
    const float v = in[(size_t)(by + r) * C + bx + tx];
    t[r][tx] = v;
    if (outp) outp[(size_t)(by + r) * C + bx + tx] = f2bf(v);
  }
  __syncthreads();
  if (outt) {
    #pragma unroll
    for (int rr = 0; rr < 16; ++rr) {
      const int c = ty * 16 + rr;
      outt[(size_t)(bx + c) * R + by + tx] = f2bf(t[tx][c]);
    }
  }
}

// ---------------- Frobenius norm (deterministic two-stage) ----------------
__global__ void __launch_bounds__(256)
k_frob(const float* __restrict__ M_, float* __restrict__ partial, int m)
{
  const int row = blockIdx.x;
  float s = 0.f;
  for (int c = threadIdx.x; c < m; c += 256) {
    const float v = M_[(size_t)row * m + c];
    s += v * v;
  }
  __shared__ float red[256];
  red[threadIdx.x] = s; __syncthreads();
  for (int o = 128; o > 0; o >>= 1) {
    if (threadIdx.x < o) red[threadIdx.x] += red[threadIdx.x + o];
    __syncthreads();
  }
  if (threadIdx.x == 0) partial[row] = red[0];
}

__global__ void __launch_bounds__(256)
k_norm_fin(const float* __restrict__ partial, float* __restrict__ rnorm, int m)
{
  float s = 0.f;
  for (int i = threadIdx.x; i < m; i += 256) s += partial[i];
  __shared__ float red[256];
  red[threadIdx.x] = s; __syncthreads();
  for (int o = 128; o > 0; o >>= 1) {
    if (threadIdx.x < o) red[threadIdx.x] += red[threadIdx.x + o];
    __syncthreads();
  }
  if (threadIdx.x == 0) rnorm[0] = 1.0f / (sqrtf(red[0]) + 1e-12f);
}

__global__ void __launch_bounds__(256)
k_scale_g(const float* __restrict__ FtF, const float* __restrict__ rnorm,
          s16* __restrict__ g0, int total)
{
  const int i = blockIdx.x * 256 + threadIdx.x;
  if (i < total) g0[i] = f2bf(FtF[i] * rnorm[0]);
}

// s[k][j] = (gamma * lamS_j)^(2^k), k = 0..5
__global__ void __launch_bounds__(256)
k_colscale(const float* __restrict__ lam, float* __restrict__ s, int n)
{
  const int j = blockIdx.x * 256 + threadIdx.x;
  if (j < n) {
    float v = 0.8f * lam[j];
    #pragma unroll
    for (int k = 0; k < 6; ++k) { s[(size_t)k * n + j] = v; v = v * v; }
  }
}

// ---------------- driver ----------------
extern "C" void kernel_launch(void* const* d_in, const int* in_sizes, int n_in,
                              void* d_out, int out_size, void* d_ws, size_t ws_size,
                              hipStream_t stream)
{
  const float* X   = (const float*)d_in[0];   // (m, n)
  const float* F   = (const float*)d_in[1];   // (m, m)
  const float* Q   = (const float*)d_in[2];   // (n, n)
  const float* lam = (const float*)d_in[3];   // (n,)

  int m = 1;
  while ((long long)m * m < (long long)in_sizes[1]) ++m;   // 512
  const int n = in_sizes[0] / m;                           // 4096

  char* w = (char*)d_ws;
  auto take = [&](size_t bytes) -> void* {
    char* p = w;
    w += (bytes + 255) & ~(size_t)255;
    return (void*)p;
  };

  s16*   Qbf   = (s16*)take((size_t)n * n * 2);   // Q_S          (bf16, row-major)
  s16*   QTbf  = (s16*)take((size_t)n * n * 2);   // Q_S^T        (bf16, row-major)
  s16*   Xbf   = (s16*)take((size_t)m * n * 2);
  s16*   FTbf  = (s16*)take((size_t)m * m * 2);   // F^T
  s16*   g[6];
  for (int k = 0; k < 6; ++k) g[k] = (s16*)take((size_t)m * m * 2);  // gF^(2^k)
  float* FtF   = (float*)take((size_t)m * m * 4);
  float* gsq   = (float*)take((size_t)m * m * 4); // fp32 scratch for squarings
  float* Zt    = (float*)take((size_t)m * n * 4); // running series S_k (fp32)
  s16*   ZbT0  = (s16*)take((size_t)m * n * 2);   // S_k^T bf16 (double-buffered)
  s16*   ZbT1  = (s16*)take((size_t)m * n * 2);
  s16*   ZbN   = (s16*)take((size_t)m * n * 2);   // final S bf16, plain layout
  float* scal  = (float*)take((size_t)6 * n * 4);
  float* part  = (float*)take((size_t)m * 4);
  float* rno   = (float*)take(256);
  (void)ws_size; (void)n_in; (void)out_size;

  const dim3 blk(256);

  // 1) conversions
  k_cvt_dual<<<dim3(n / 64, m / 64), blk, 0, stream>>>(X, Xbf, nullptr, m, n);
  k_cvt_dual<<<dim3(n / 64, n / 64), blk, 0, stream>>>(Q, Qbf, QTbf, n, n);
  k_cvt_dual<<<dim3(m / 64, m / 64), blk, 0, stream>>>(F, nullptr, FTbf, m, m);

  // 2) FtF = F^T F   (A = F^T, BT = F^T  =>  B = F)
  gemm_bt<<<dim3(m / BN, m / BM), blk, 0, stream>>>(FTbf, FTbf, FtF, m, m, m,
                                                    nullptr, nullptr, nullptr, nullptr);
  // 3) 1/(||FtF||_F + eps), g0 = bf16(FtF * rnorm)
  k_frob<<<dim3(m), blk, 0, stream>>>(FtF, part, m);
  k_norm_fin<<<dim3(1), blk, 0, stream>>>(part, rno, m);
  k_scale_g<<<dim3((m * m + 255) / 256), blk, 0, stream>>>(FtF, rno, g[0], m * m);

  // 4) squaring chain g[k+1] = bf16(g[k] @ g[k])   (symmetric => BT = g[k])
  for (int k = 0; k < 5; ++k)
    gemm_bt<<<dim3(m / BN, m / BM), blk, 0, stream>>>(g[k], g[k], gsq, m, m, m,
                                                      nullptr, nullptr, g[k + 1], nullptr);

  // 5) column scales (gamma*lam)^(2^k)
  k_colscale<<<dim3((n + 255) / 256), blk, 0, stream>>>(lam, scal, n);

  // 6) Xt = X @ Q_S  (BT = Q_S^T); S_0 = Xt (fp32 in Zt, bf16-transposed in ZbT0)
  gemm_bt<<<dim3(n / BN, m / BM), blk, 0, stream>>>(Xbf, QTbf, Zt, m, n, n,
                                                    nullptr, nullptr, nullptr, ZbT0);

  // 7) doubling: S_{k+1} = S_k + gF^(2^k) @ S_k * colscale_k   (64 Neumann terms)
  s16* zbt[2] = { ZbT0, ZbT1 };
  for (int k = 0; k < 6; ++k) {
    const bool last = (k == 5);
    gemm_bt<<<dim3(n / BN, m / BM), blk, 0, stream>>>(
        g[k], zbt[k & 1], Zt, m, n, m,
        scal + (size_t)k * n, Zt,
        last ? ZbN : nullptr, last ? nullptr : zbt[(k + 1) & 1]);
  }

  // 8) Z = S @ Q_S^T  (A = S bf16, BT = Q_S)  -> d_out (fp32)
  gemm_bt<<<dim3(n / BN, m / BM), blk, 0, stream>>>(ZbN, Qbf, (float*)d_out, m, n, n,
                                                    nullptr, nullptr, nullptr, nullptr);
}

// Round 3
// 296.322 us; speedup vs baseline: 1.7006x; 1.7006x over previous
//
#include <hip/hip_runtime.h>
#include <stdint.h>

typedef short s16;
typedef __attribute__((ext_vector_type(8))) short short8;  // 8 bf16 (4 VGPRs)
typedef __attribute__((ext_vector_type(4))) float f32x4;

__device__ __forceinline__ s16 f2bf(float f) {
  union { float f; uint32_t u; } v; v.f = f;
  uint32_t u = v.u;
  uint32_t r = (u + 0x7fffu + ((u >> 16) & 1u)) >> 16;  // RNE
  return (s16)(uint16_t)r;
}

#define GLOBAL_AS __attribute__((address_space(1)))
#define LDS_AS    __attribute__((address_space(3)))
__device__ __forceinline__ void gload_lds16(const void* g, void* l) {
  __builtin_amdgcn_global_load_lds((const GLOBAL_AS uint32_t*)g, (LDS_AS uint32_t*)l, 16, 0, 0);
}

// ---------------- GEMM: C(MxN) = A(MxK,row) @ B, B given as BT(NxK,row) -------
// Proven 2-barrier single-buffer K-loop (round-1 sync structure), BK=64,
// XOR-swizzled LDS via pre-swizzled global source (rule #21: swizzle both
// sides — linear LDS dest, same involution on source and read).
// gridDim.z = K-split; z writes C + z*M*N (fp32 partials). colscale/addend/
// bf16 side-outputs are only used on gridDim.z==1 launches.
#define BM 128
#define BN 128
#define BK 64

__global__ void __launch_bounds__(256, 2)
gemm_bt(const s16* __restrict__ A, const s16* __restrict__ BT,
        float* C,                       // may be null
        int M, int N, int K, int Kc,
        const float* __restrict__ colscale,
        const float* addend,            // may alias C
        s16* __restrict__ obf_n, s16* __restrict__ obf_t)
{
  __shared__ alignas(16) s16 lta[BM * BK];
  __shared__ alignas(16) s16 ltb[BN * BK];
  const int tid  = threadIdx.x;
  const int lane = tid & 63;
  const int wave = tid >> 6;
  const int wr = wave >> 1, wc = wave & 1;
  const int bm0 = blockIdx.y * BM;
  const int bn0 = blockIdx.x * BN;
  const int k0  = blockIdx.z * Kc;

  f32x4 acc[4][4];
  #pragma unroll
  for (int i = 0; i < 4; ++i)
    #pragma unroll
    for (int j = 0; j < 4; ++j)
      #pragma unroll
      for (int r = 0; r < 4; ++r) acc[i][j][r] = 0.0f;

  // staging: lane l -> row wave*8 + (l>>3), k-group ((l&7)^(l>>3)); LDS dest is
  // linear (wave-uniform base + lane*16B), so the XOR lives in the global src.
  const int lrow = lane >> 3;
  const int lke  = ((lane & 7) ^ lrow) * 8;
  const s16* Ab = A  + (size_t)(bm0 + wave * 8 + lrow) * K + k0 + lke;
  const s16* Bb = BT + (size_t)(bn0 + wave * 8 + lrow) * K + k0 + lke;

  const int fr = lane & 15;
  const int k8 = (lane >> 4) * 8;
  const int sw = (fr & 7) * 8;       // read-side XOR: row&7 == fr&7

  const int nt = Kc / BK;
  for (int t = 0; t < nt; ++t) {
    const int ko = t * BK;
    #pragma unroll
    for (int s = 0; s < 4; ++s) {
      gload_lds16(Ab + (size_t)s * 32 * K + ko, &lta[s * 2048 + wave * 512]);
      gload_lds16(Bb + (size_t)s * 32 * K + ko, &ltb[s * 2048 + wave * 512]);
    }
    __syncthreads();   // vmcnt(0) drained: tile fully staged

    short8 af[2][4], bfv[2][4];
    #pragma unroll
    for (int kk = 0; kk < 2; ++kk) {
      #pragma unroll
      for (int i = 0; i < 4; ++i)
        af[kk][i] = *(const short8*)&lta[(wr * 64 + i * 16 + fr) * BK + ((kk * 32 + k8) ^ sw)];
      #pragma unroll
      for (int j = 0; j < 4; ++j)
        bfv[kk][j] = *(const short8*)&ltb[(wc * 64 + j * 16 + fr) * BK + ((kk * 32 + k8) ^ sw)];
    }
    #pragma unroll
    for (int kk = 0; kk < 2; ++kk)
      #pragma unroll
      for (int i = 0; i < 4; ++i)
        #pragma unroll
        for (int j = 0; j < 4; ++j)
          acc[i][j] = __builtin_amdgcn_mfma_f32_16x16x32_bf16(af[kk][i], bfv[kk][j], acc[i][j], 0, 0, 0);
    __syncthreads();   // all waves done reading before next tile overwrites
  }

  // epilogue — C/D layout: col = lane&15, row = (lane>>4)*4 + reg
  float* Cz = C ? C + (size_t)blockIdx.z * M * N : nullptr;
  const int r0 = (lane >> 4) * 4;
  const int cl = lane & 15;
  #pragma unroll
  for (int i = 0; i < 4; ++i) {
    const int gm = bm0 + wr * 64 + i * 16 + r0;
    #pragma unroll
    for (int j = 0; j < 4; ++j) {
      const int gn = bn0 + wc * 64 + j * 16 + cl;
      const float cs = colscale ? colscale[gn] : 1.0f;
      #pragma unroll
      for (int r = 0; r < 4; ++r) {
        const size_t idx = (size_t)(gm + r) * N + gn;
        float v = acc[i][j][r] * cs;
        if (addend) v += addend[idx];
        if (Cz) Cz[idx] = v;
        if (obf_n) obf_n[idx] = f2bf(v);
        if (obf_t) obf_t[(size_t)gn * M + (gm + r)] = f2bf(v);
      }
    }
  }
}

// ------- combine: out = (sum_z parts[z]) * colscale + addend; fp32 + bf16 outs
__global__ void __launch_bounds__(256)
k_combine(const float* __restrict__ parts, int KS, int M, int N,
          const float* __restrict__ colscale, const float* __restrict__ addend,
          float* C, s16* __restrict__ obf_n, s16* __restrict__ obf_t)
{
  __shared__ float tb[64][65];
  const int bx = blockIdx.x * 64, by = blockIdx.y * 64;
  const int tx = threadIdx.x & 63, ty = threadIdx.x >> 6;
  const int col = bx + tx;
  const float cs = colscale ? colscale[col] : 1.0f;
  const size_t MN = (size_t)M * N;
  #pragma unroll
  for (int rr = 0; rr < 16; ++rr) {
    const int r = ty * 16 + rr;
    const size_t idx = (size_t)(by + r) * N + col;
    float v = parts[idx];
    for (int z = 1; z < KS; ++z) v += parts[(size_t)z * MN + idx];
    v *= cs;
    if (addend) v += addend[idx];
    if (C) C[idx] = v;
    if (obf_n) obf_n[idx] = f2bf(v);
    tb[r][tx] = v;
  }
  if (obf_t) {
    __syncthreads();
    #pragma unroll
    for (int rr = 0; rr < 16; ++rr) {
      const int c = ty * 16 + rr;
      obf_t[(size_t)(bx + c) * M + by + tx] = f2bf(tb[tx][c]);
    }
  }
}

// ------- fp32 -> bf16 convert, plain and/or transposed (64x64 tiles) ---------
__global__ void __launch_bounds__(256)
k_cvt_dual(const float* __restrict__ in, s16* __restrict__ outp, s16* __restrict__ outt,
           int R, int C)
{
  __shared__ float t[64][65];
  const int bx = blockIdx.x * 64, by = blockIdx.y * 64;
  const int tx = threadIdx.x & 63, ty = threadIdx.x >> 6;
  #pragma unroll
  for (int rr = 0; rr < 16; ++rr) {
    const int r = ty * 16 + rr;
    const float v = in[(size_t)(by + r) * C + bx + tx];
    t[r][tx] = v;
    if (outp) outp[(size_t)(by + r) * C + bx + tx] = f2bf(v);
  }
  if (outt) {
    __syncthreads();
    #pragma unroll
    for (int rr = 0; rr < 16; ++rr) {
      const int c = ty * 16 + rr;
      outt[(size_t)(bx + c) * R + by + tx] = f2bf(t[tx][c]);
    }
  }
}

// ------- Frobenius norm (deterministic two-stage) ----------------------------
__global__ void __launch_bounds__(256)
k_frob(const float* __restrict__ M_, float* __restrict__ partial, int m)
{
  const int row = blockIdx.x;
  float s = 0.f;
  for (int c = threadIdx.x; c < m; c += 256) {
    const float v = M_[(size_t)row * m + c];
    s += v * v;
  }
  __shared__ float red[256];
  red[threadIdx.x] = s; __syncthreads();
  for (int o = 128; o > 0; o >>= 1) {
    if (threadIdx.x < o) red[threadIdx.x] += red[threadIdx.x + o];
    __syncthreads();
  }
  if (threadIdx.x == 0) partial[row] = red[0];
}

__global__ void __launch_bounds__(256)
k_norm_fin(const float* __restrict__ partial, float* __restrict__ rnorm, int m)
{
  float s = 0.f;
  for (int i = threadIdx.x; i < m; i += 256) s += partial[i];
  __shared__ float red[256];
  red[threadIdx.x] = s; __syncthreads();
  for (int o = 128; o > 0; o >>= 1) {
    if (threadIdx.x < o) red[threadIdx.x] += red[threadIdx.x + o];
    __syncthreads();
  }
  if (threadIdx.x == 0) rnorm[0] = 1.0f / (sqrtf(red[0]) + 1e-12f);
}

__global__ void __launch_bounds__(256)
k_scale_g(const float* __restrict__ FtF, const float* __restrict__ rnorm,
          s16* __restrict__ g0, int total)
{
  const int i = blockIdx.x * 256 + threadIdx.x;
  if (i < total) g0[i] = f2bf(FtF[i] * rnorm[0]);
}

// s[k][j] = (gamma * lamS_j)^(2^k), k = 0..2
__global__ void __launch_bounds__(256)
k_colscale(const float* __restrict__ lam, float* __restrict__ s, int n)
{
  const int j = blockIdx.x * 256 + threadIdx.x;
  if (j < n) {
    float v = 0.8f * lam[j];
    #pragma unroll
    for (int k = 0; k < 3; ++k) { s[(size_t)k * n + j] = v; v = v * v; }
  }
}

// ---------------- driver ----------------
extern "C" void kernel_launch(void* const* d_in, const int* in_sizes, int n_in,
                              void* d_out, int out_size, void* d_ws, size_t ws_size,
                              hipStream_t stream)
{
  const float* X   = (const float*)d_in[0];   // (m, n)
  const float* F   = (const float*)d_in[1];   // (m, m)
  const float* Q   = (const float*)d_in[2];   // (n, n)
  const float* lam = (const float*)d_in[3];   // (n,)

  int m = 1;
  while ((long long)m * m < (long long)in_sizes[1]) ++m;   // 512
  const int n = in_sizes[0] / m;                           // 4096

  char* w = (char*)d_ws;
  auto take = [&](size_t bytes) -> void* {
    char* p = w;
    w += (bytes + 255) & ~(size_t)255;
    return (void*)p;
  };

  // Overlays (total ~91.3 MB, below the ~98 MB proven to fit in round 1):
  //  Qslot:  step-6 fp32 partials (4*m*n floats == n*n*2 bytes exactly),
  //          THEN Qbf (Q converted after step 6 from untouched d_in).
  //  QTslot: QTbf (dead after step 6), THEN step-7/8 fp32 partials.
  char*  Qslot  = (char*)take((size_t)n * n * 2);
  char*  QTslot = (char*)take((size_t)n * n * 2);
  s16*   Xbf  = (s16*)take((size_t)m * n * 2);
  s16*   FTbf = (s16*)take((size_t)m * m * 2);   // F^T
  s16*   g[3];
  for (int k = 0; k < 3; ++k) g[k] = (s16*)take((size_t)m * m * 2);  // gF^(2^k)
  float* FtF  = (float*)take((size_t)m * m * 4);
  float* Zt   = (float*)take((size_t)m * n * 4); // running series S_k (fp32)
  s16*   ZbT0 = (s16*)take((size_t)m * n * 2);   // S_k^T bf16 (dbl-buffered)
  s16*   ZbT1 = (s16*)take((size_t)m * n * 2);
  s16*   ZbN  = ZbT1;                            // ZbT1 dead before ZbN written
  float* scal = (float*)take((size_t)3 * n * 4);
  float* part = (float*)take((size_t)m * 4);
  float* rno  = (float*)take(256);
  (void)ws_size; (void)n_in; (void)out_size;

  s16*   Qbf     = (s16*)Qslot;
  float* parts6  = (float*)Qslot;    // 4 * m*n floats fits exactly in n*n*2 B
  s16*   QTbf    = (s16*)QTslot;
  float* parts78 = (float*)QTslot;   // 4 * m*n floats fits in n*n*2 B

  const int KS = 4;                  // K-split for m x n GEMMs: 512 blocks
  const dim3 blk(256);

  // 1) conversions (Q -> transposed bf16 only, for now)
  k_cvt_dual<<<dim3(n / 64, m / 64), blk, 0, stream>>>(X, Xbf, nullptr, m, n);
  k_cvt_dual<<<dim3(n / 64, n / 64), blk, 0, stream>>>(Q, nullptr, QTbf, n, n);
  k_cvt_dual<<<dim3(m / 64, m / 64), blk, 0, stream>>>(F, nullptr, FTbf, m, m);

  // 2) FtF = F^T F  (A = F^T, BT = F^T => B = F)
  gemm_bt<<<dim3(m / BN, m / BM, 1), blk, 0, stream>>>(FTbf, FTbf, FtF, m, m, m, m,
                                                       nullptr, nullptr, nullptr, nullptr);
  // 3) 1/(||FtF||_F + eps); g0 = bf16(FtF * rnorm)
  k_frob<<<dim3(m), blk, 0, stream>>>(FtF, part, m);
  k_norm_fin<<<dim3(1), blk, 0, stream>>>(part, rno, m);
  k_scale_g<<<dim3((m * m + 255) / 256), blk, 0, stream>>>(FtF, rno, g[0], m * m);

  // 4) squaring chain: g^2, g^4 (symmetric => BT = g[k]); bf16 out only
  for (int k = 0; k < 2; ++k)
    gemm_bt<<<dim3(m / BN, m / BM, 1), blk, 0, stream>>>(g[k], g[k], nullptr, m, m, m, m,
                                                         nullptr, nullptr, g[k + 1], nullptr);

  // 5) column scales (gamma*lam)^(2^k), k=0..2
  k_colscale<<<dim3((n + 255) / 256), blk, 0, stream>>>(lam, scal, n);

  // 6) Xt = X @ Q_S (BT = Q_S^T), K-split into parts6 -> Zt fp32, ZbT0 bf16^T
  gemm_bt<<<dim3(n / BN, m / BM, KS), blk, 0, stream>>>(Xbf, QTbf, parts6, m, n, n, n / KS,
                                                        nullptr, nullptr, nullptr, nullptr);
  k_combine<<<dim3(n / 64, m / 64), blk, 0, stream>>>(parts6, KS, m, n,
                                                      nullptr, nullptr, Zt, nullptr, ZbT0);

  // 6c) now convert Q plain (overwrites parts6 slot; Q re-read from d_in)
  k_cvt_dual<<<dim3(n / 64, n / 64), blk, 0, stream>>>(Q, Qbf, nullptr, n, n);

  // 7) 3 doublings: S_{k+1} = S_k + g^(2^k) @ S_k * (gamma lam)^(2^k)  (8 terms)
  s16* zin = ZbT0; s16* zout = ZbT1;
  for (int k = 0; k < 3; ++k) {
    const bool last = (k == 2);
    gemm_bt<<<dim3(n / BN, m / BM, KS), blk, 0, stream>>>(g[k], zin, parts78, m, n, m, m / KS,
                                                          nullptr, nullptr, nullptr, nullptr);
    k_combine<<<dim3(n / 64, m / 64), blk, 0, stream>>>(parts78, KS, m, n,
                                                        scal + (size_t)k * n, Zt,
                                                        last ? nullptr : Zt,
                                                        last ? ZbN : nullptr,
                                                        last ? nullptr : zout);
    s16* tmp = zin; zin = zout; zout = tmp;
  }

  // 8) Z = S @ Q_S^T  (A = S bf16, BT = Q_S) -> d_out fp32
  gemm_bt<<<dim3(n / BN, m / BM, KS), blk, 0, stream>>>(ZbN, Qbf, parts78, m, n, n, n / KS,
                                                        nullptr, nullptr, nullptr, nullptr);
  k_combine<<<dim3(n / 64, m / 64), blk, 0, stream>>>(parts78, KS, m, n,
                                                      nullptr, nullptr, (float*)d_out, nullptr, nullptr);
}

// Round 4
// 199.947 us; speedup vs baseline: 2.5203x; 1.4820x over previous
//
#include <hip/hip_runtime.h>
#include <stdint.h>

typedef short s16;
typedef __attribute__((ext_vector_type(8))) short short8;  // 8 bf16 (4 VGPRs)
typedef __attribute__((ext_vector_type(4))) float f32x4;
typedef __attribute__((ext_vector_type(4))) short short4v;

__device__ __forceinline__ s16 f2bf(float f) {
  union { float f; uint32_t u; } v; v.f = f;
  uint32_t u = v.u;
  uint32_t r = (u + 0x7fffu + ((u >> 16) & 1u)) >> 16;  // RNE
  return (s16)(uint16_t)r;
}

#define GLOBAL_AS __attribute__((address_space(1)))
#define LDS_AS    __attribute__((address_space(3)))
__device__ __forceinline__ void gload_lds16(const void* g, void* l) {
  __builtin_amdgcn_global_load_lds((const GLOBAL_AS uint32_t*)g, (LDS_AS uint32_t*)l, 16, 0, 0);
}

// ---------------- GEMM: C(MxN) = A(MxK,row) @ B, B given as BT(NxK,row) -------
// Proven round-3 sync structure (single-buffer, 2 barriers per K-tile), BK=64,
// XOR-swizzled LDS via pre-swizzled global source (linear LDS dest; same
// involution on source and read). Template on tile shape only; 4 waves as 2x2.
// gridDim.z>1: K-split, z writes C + z*M*N (fp32 partials), epilogue extras
// must be null. gridDim.z==1: fused epilogue
//   v = acc * (rowscale?rowscale[row]:1) + (addend?addend[idx]:0)
//   C[idx]=v (if C); obf_n[idx]=bf16(v); obf_t[col*M+row]=bf16(v).
template<int BM_, int BN_>
__global__ void __launch_bounds__(256, 2)
gemm_t(const s16* __restrict__ A, const s16* __restrict__ BT,
       float* C, int M, int N, int K, int Kc,
       const float* __restrict__ rowscale,
       const float* addend,            // may alias C (in-place); no restrict
       s16* __restrict__ obf_n, s16* __restrict__ obf_t)
{
  constexpr int SWA = BM_ / 32;       // staging sweeps (32 rows x 64k each)
  constexpr int SWB = BN_ / 32;
  constexpr int WM  = BM_ / 2;        // per-wave tile (2x2 wave grid)
  constexpr int WN  = BN_ / 2;
  constexpr int IM  = WM / 16;
  constexpr int JN  = WN / 16;

  __shared__ alignas(16) s16 lta[BM_ * 64];
  __shared__ alignas(16) s16 ltb[BN_ * 64];
  const int tid  = threadIdx.x;
  const int lane = tid & 63;
  const int wave = tid >> 6;
  const int wr = wave >> 1, wc = wave & 1;
  const int bm0 = blockIdx.y * BM_;
  const int bn0 = blockIdx.x * BN_;
  const int k0  = blockIdx.z * Kc;

  f32x4 acc[IM][JN];
  #pragma unroll
  for (int i = 0; i < IM; ++i)
    #pragma unroll
    for (int j = 0; j < JN; ++j)
      #pragma unroll
      for (int r = 0; r < 4; ++r) acc[i][j][r] = 0.0f;

  // staging: lane l -> row wave*8 + (l>>3), k-group ((l&7)^(l>>3)); LDS dest
  // linear (base + lane*16B), XOR lives in the global source address.
  const int lrow = lane >> 3;
  const int lke  = ((lane & 7) ^ lrow) * 8;
  const s16* Ab = A  + (size_t)(bm0 + wave * 8 + lrow) * K + k0 + lke;
  const s16* Bb = BT + (size_t)(bn0 + wave * 8 + lrow) * K + k0 + lke;

  const int fr = lane & 15;
  const int k8 = (lane >> 4) * 8;
  const int sw = (fr & 7) * 8;       // read-side XOR: row&7 == fr&7

  const int nt = Kc / 64;
  for (int t = 0; t < nt; ++t) {
    const int ko = t * 64;
    #pragma unroll
    for (int s = 0; s < SWA; ++s)
      gload_lds16(Ab + (size_t)s * 32 * K + ko, &lta[s * 2048 + wave * 512]);
    #pragma unroll
    for (int s = 0; s < SWB; ++s)
      gload_lds16(Bb + (size_t)s * 32 * K + ko, &ltb[s * 2048 + wave * 512]);
    __syncthreads();   // drains vmcnt(0): tile fully staged

    short8 af[2][IM], bfv[2][JN];
    #pragma unroll
    for (int kk = 0; kk < 2; ++kk) {
      #pragma unroll
      for (int i = 0; i < IM; ++i)
        af[kk][i] = *(const short8*)&lta[(wr * WM + i * 16 + fr) * 64 + ((kk * 32 + k8) ^ sw)];
      #pragma unroll
      for (int j = 0; j < JN; ++j)
        bfv[kk][j] = *(const short8*)&ltb[(wc * WN + j * 16 + fr) * 64 + ((kk * 32 + k8) ^ sw)];
    }
    #pragma unroll
    for (int kk = 0; kk < 2; ++kk)
      #pragma unroll
      for (int i = 0; i < IM; ++i)
        #pragma unroll
        for (int j = 0; j < JN; ++j)
          acc[i][j] = __builtin_amdgcn_mfma_f32_16x16x32_bf16(af[kk][i], bfv[kk][j], acc[i][j], 0, 0, 0);
    __syncthreads();   // all waves done reading before next tile overwrites
  }

  // epilogue — C/D layout: col = lane&15, row = (lane>>4)*4 + reg
  float* Cz = C ? C + (size_t)blockIdx.z * M * N : nullptr;
  const int r0 = (lane >> 4) * 4;
  const int cl = lane & 15;
  #pragma unroll
  for (int i = 0; i < IM; ++i) {
    const int gm = bm0 + wr * WM + i * 16 + r0;
    #pragma unroll
    for (int j = 0; j < JN; ++j) {
      const int gn = bn0 + wc * WN + j * 16 + cl;
      #pragma unroll
      for (int r = 0; r < 4; ++r) {
        const size_t idx = (size_t)(gm + r) * N + gn;
        float v = acc[i][j][r];
        if (rowscale) v *= rowscale[gm + r];
        if (addend)   v += addend[idx];
        if (Cz)    Cz[idx] = v;
        if (obf_n) obf_n[idx] = f2bf(v);
        if (obf_t) obf_t[(size_t)gn * M + (gm + r)] = f2bf(v);
      }
    }
  }
}

// ------- combine (KS=2): v = parts[i] + parts[MN+i]; fp32 + optional bf16 ----
// NOTE: C may alias parts slice 0 (same element read-then-written per thread).
__global__ void __launch_bounds__(256)
k_combine2(const float* parts, size_t MN,
           float* C, s16* __restrict__ obf_n)
{
  const size_t i4 = ((size_t)blockIdx.x * 256 + threadIdx.x) * 4;
  if (i4 >= MN) return;
  f32x4 a = *(const f32x4*)(parts + i4);
  f32x4 b = *(const f32x4*)(parts + MN + i4);
  f32x4 v;
  #pragma unroll
  for (int r = 0; r < 4; ++r) v[r] = a[r] + b[r];
  if (C) *(f32x4*)(C + i4) = v;
  if (obf_n) {
    short4v o;
    #pragma unroll
    for (int r = 0; r < 4; ++r) o[r] = f2bf(v[r]);
    *(short4v*)(obf_n + i4) = o;
  }
}

// ------- fp32 -> bf16 convert, plain and/or transposed (64x64 tiles) ---------
__global__ void __launch_bounds__(256)
k_cvt_dual(const float* __restrict__ in, s16* __restrict__ outp, s16* __restrict__ outt,
           int R, int C)
{
  __shared__ float t[64][65];
  const int bx = blockIdx.x * 64, by = blockIdx.y * 64;
  const int tx = threadIdx.x & 63, ty = threadIdx.x >> 6;
  #pragma unroll
  for (int rr = 0; rr < 16; ++rr) {
    const int r = ty * 16 + rr;
    const float v = in[(size_t)(by + r) * C + bx + tx];
    t[r][tx] = v;
    if (outp) outp[(size_t)(by + r) * C + bx + tx] = f2bf(v);
  }
  if (outt) {
    __syncthreads();
    #pragma unroll
    for (int rr = 0; rr < 16; ++rr) {
      const int c = ty * 16 + rr;
      outt[(size_t)(bx + c) * R + by + tx] = f2bf(t[tx][c]);
    }
  }
}

// ------- Frobenius norm (deterministic two-stage) ----------------------------
__global__ void __launch_bounds__(256)
k_frob(const float* __restrict__ M_, float* __restrict__ partial, int m)
{
  const int row = blockIdx.x;
  float s = 0.f;
  for (int c = threadIdx.x; c < m; c += 256) {
    const float v = M_[(size_t)row * m + c];
    s += v * v;
  }
  __shared__ float red[256];
  red[threadIdx.x] = s; __syncthreads();
  for (int o = 128; o > 0; o >>= 1) {
    if (threadIdx.x < o) red[threadIdx.x] += red[threadIdx.x + o];
    __syncthreads();
  }
  if (threadIdx.x == 0) partial[row] = red[0];
}

__global__ void __launch_bounds__(256)
k_norm_fin(const float* __restrict__ partial, float* __restrict__ rnorm, int m)
{
  float s = 0.f;
  for (int i = threadIdx.x; i < m; i += 256) s += partial[i];
  __shared__ float red[256];
  red[threadIdx.x] = s; __syncthreads();
  for (int o = 128; o > 0; o >>= 1) {
    if (threadIdx.x < o) red[threadIdx.x] += red[threadIdx.x + o];
    __syncthreads();
  }
  if (threadIdx.x == 0) rnorm[0] = 1.0f / (sqrtf(red[0]) + 1e-12f);
}

__global__ void __launch_bounds__(256)
k_scale_g(const float* __restrict__ FtF, const float* __restrict__ rnorm,
          s16* __restrict__ g0, int total)
{
  const int i = blockIdx.x * 256 + threadIdx.x;
  if (i < total) g0[i] = f2bf(FtF[i] * rnorm[0]);
}

// s[k][j] = (gamma * lamS_j)^(2^k), k = 0..2  (row scales of the St chain)
__global__ void __launch_bounds__(256)
k_colscale(const float* __restrict__ lam, float* __restrict__ s, int n)
{
  const int j = blockIdx.x * 256 + threadIdx.x;
  if (j < n) {
    float v = 0.8f * lam[j];
    #pragma unroll
    for (int k = 0; k < 3; ++k) { s[(size_t)k * n + j] = v; v = v * v; }
  }
}

// ---------------- driver ----------------
extern "C" void kernel_launch(void* const* d_in, const int* in_sizes, int n_in,
                              void* d_out, int out_size, void* d_ws, size_t ws_size,
                              hipStream_t stream)
{
  const float* X   = (const float*)d_in[0];   // (m, n)
  const float* F   = (const float*)d_in[1];   // (m, m)
  const float* Q   = (const float*)d_in[2];   // (n, n)
  const float* lam = (const float*)d_in[3];   // (n,)

  int m = 1;
  while ((long long)m * m < (long long)in_sizes[1]) ++m;   // 512
  const int n = in_sizes[0] / m;                           // 4096
  const size_t MN = (size_t)m * n;                         // 2M elements

  char* w = (char*)d_ws;
  auto take = [&](size_t bytes) -> void* {
    char* p = w;
    w += (bytes + 255) & ~(size_t)255;
    return (void*)p;
  };

  // Transposed-chain buffers. Total ~95 MB (< 98 MB proven in round 1).
  s16*   Qbf  = (s16*)take((size_t)n * n * 2);   // Q        (bf16)
  s16*   QTbf = (s16*)take((size_t)n * n * 2);   // Q^T      (bf16)
  s16*   Xbf  = (s16*)take(MN * 2);              // X        (bf16 plain)
  s16*   FTbf = (s16*)take((size_t)m * m * 2);   // F^T
  s16*   g[3];
  for (int k = 0; k < 3; ++k) g[k] = (s16*)take((size_t)m * m * 2);  // gF^(2^k)
  float* FtF  = (float*)take((size_t)m * m * 4);
  float* scal = (float*)take((size_t)3 * n * 4);
  float* part = (float*)take((size_t)m * 4);
  float* rno  = (float*)take(256);
  float* Zt   = (float*)take(MN * 4);            // running St fp32 (n x m)
  float* spare= (float*)take(MN * 4);            // K-split partial slice 1
  s16*   Sb0  = (s16*)take(MN * 2);              // St bf16 ping
  s16*   Sb1  = (s16*)take(MN * 2);              // St bf16 pong / S plain
  (void)spare; (void)ws_size; (void)n_in; (void)out_size;

  float* parts  = Zt;    // KS=2 partials overlay [Zt][spare]; combine writes
                         // C=Zt element-wise after reading both slices (safe:
                         // same thread reads slice0[i] before writing C[i]).
  s16*   Splain = Sb1;   // Sb1 dead after doubling k=1 consumed it

  const dim3 blk(256);

  // 1) conversions (Q: single pass producing both layouts)
  k_cvt_dual<<<dim3(n / 64, m / 64), blk, 0, stream>>>(X, Xbf, nullptr, m, n);
  k_cvt_dual<<<dim3(n / 64, n / 64), blk, 0, stream>>>(Q, Qbf, QTbf, n, n);
  k_cvt_dual<<<dim3(m / 64, m / 64), blk, 0, stream>>>(F, nullptr, FTbf, m, m);

  // 2) FtF = F^T F  (A = F^T, BT = F^T => B = F)
  gemm_t<64, 64><<<dim3(m / 64, m / 64, 1), blk, 0, stream>>>(
      FTbf, FTbf, FtF, m, m, m, m, nullptr, nullptr, nullptr, nullptr);

  // 3) 1/(||FtF||_F + eps); g0 = bf16(FtF * rnorm)
  k_frob<<<dim3(m), blk, 0, stream>>>(FtF, part, m);
  k_norm_fin<<<dim3(1), blk, 0, stream>>>(part, rno, m);
  k_scale_g<<<dim3((m * m + 255) / 256), blk, 0, stream>>>(FtF, rno, g[0], m * m);

  // 4) squarings: g[k+1] = bf16(g[k] @ g[k])  (exactly symmetric each step)
  for (int k = 0; k < 2; ++k)
    gemm_t<64, 64><<<dim3(m / 64, m / 64, 1), blk, 0, stream>>>(
        g[k], g[k], nullptr, m, m, m, m, nullptr, nullptr, g[k + 1], nullptr);

  // 5) row scales (gamma*lam)^(2^k), k=0..2
  k_colscale<<<dim3((n + 255) / 256), blk, 0, stream>>>(lam, scal, n);

  // 6) St0 = Q^T X^T  (A = Q^T, BT = X),  M=n, N=m, K=n, KS=2 -> combine
  gemm_t<128, 64><<<dim3(m / 64, n / 128, 2), blk, 0, stream>>>(
      QTbf, Xbf, parts, n, m, n, n / 2, nullptr, nullptr, nullptr, nullptr);
  k_combine2<<<dim3((unsigned)(MN / 1024)), blk, 0, stream>>>(parts, MN, Zt, Sb0);

  // 7) doublings (transposed): St_{k+1} = St_k + rs_k . (St_k @ g_k)
  //    A = St_k bf16, BT = g_k (symmetric). Direct fused epilogue, 512 blocks.
  gemm_t<64, 64><<<dim3(m / 64, n / 64, 1), blk, 0, stream>>>(
      Sb0, g[0], Zt, n, m, m, m, scal + 0 * (size_t)n, Zt, Sb1, nullptr);
  gemm_t<64, 64><<<dim3(m / 64, n / 64, 1), blk, 0, stream>>>(
      Sb1, g[1], Zt, n, m, m, m, scal + 1 * (size_t)n, Zt, Sb0, nullptr);
  // last: emit only S plain (m x n) via transposed bf16 write
  gemm_t<64, 64><<<dim3(m / 64, n / 64, 1), blk, 0, stream>>>(
      Sb0, g[2], nullptr, n, m, m, m, scal + 2 * (size_t)n, Zt, nullptr, Splain);

  // 8) Z = S @ Q^T  (A = S plain, BT = Q), M=m, N=n, K=n, KS=2 -> d_out
  gemm_t<64, 128><<<dim3(n / 128, m / 64, 2), blk, 0, stream>>>(
      Splain, Qbf, parts, m, n, n, n / 2, nullptr, nullptr, nullptr, nullptr);
  k_combine2<<<dim3((unsigned)(MN / 1024)), blk, 0, stream>>>(parts, MN, (float*)d_out, nullptr);
}

// Round 5
// 184.785 us; speedup vs baseline: 2.7271x; 1.0820x over previous
//
#include <hip/hip_runtime.h>
#include <stdint.h>

typedef short s16;
typedef __attribute__((ext_vector_type(8))) short short8;  // 8 bf16 (4 VGPRs)
typedef __attribute__((ext_vector_type(4))) float f32x4;
typedef __attribute__((ext_vector_type(4))) short short4v;

__device__ __forceinline__ s16 f2bf(float f) {
  union { float f; uint32_t u; } v; v.f = f;
  uint32_t u = v.u;
  uint32_t r = (u + 0x7fffu + ((u >> 16) & 1u)) >> 16;  // RNE
  return (s16)(uint16_t)r;
}

#define GLOBAL_AS __attribute__((address_space(1)))
#define LDS_AS    __attribute__((address_space(3)))
__device__ __forceinline__ void gload_lds16(const void* g, void* l) {
  __builtin_amdgcn_global_load_lds((const GLOBAL_AS uint32_t*)g, (LDS_AS uint32_t*)l, 16, 0, 0);
}

// ---------------- GEMM: C(MxN) = A(MxK,row) @ B, B given as BT(NxK,row) -------
// Proven single-buffer 2-barrier K-loop, BK=64, XOR-swizzled LDS via
// pre-swizzled global source (linear LDS dest; same involution on read).
// SX: if true, blockIdx.x indexes the M(row/A) direction, else the N direction.
// Pick SX so blockIdx.x indexes the LARGE operand's panels: dispatch assigns
// XCD = linear_id % 8 and gx % 8 == 0 everywhere here, so same-XCD blocks then
// share a small set of large-operand panels (L2-resident) instead of streaming
// the whole large operand through every XCD's 4 MB L2.
// gridDim.z>1: K-split, z writes C + z*M*N (fp32 partials), epilogue extras
// must be null. gridDim.z==1: fused epilogue
//   v = acc * (rowscale?rowscale[row]:1) + (addend?addend[idx]:0)
//   C[idx]=v (if C); obf_n[idx]=bf16(v); obf_t[col*M+row]=bf16(v).
template<int BM_, int BN_, bool SX>
__global__ void __launch_bounds__(256, 2)
gemm_t(const s16* __restrict__ A, const s16* __restrict__ BT,
       float* C, int M, int N, int K, int Kc,
       const float* __restrict__ rowscale,
       const float* addend,            // may alias C (in-place); no restrict
       s16* __restrict__ obf_n, s16* __restrict__ obf_t)
{
  constexpr int SWA = BM_ / 32;       // staging sweeps (32 rows x 64k each)
  constexpr int SWB = BN_ / 32;
  constexpr int WM  = BM_ / 2;        // per-wave tile (2x2 wave grid)
  constexpr int WN  = BN_ / 2;
  constexpr int IM  = WM / 16;
  constexpr int JN  = WN / 16;

  __shared__ alignas(16) s16 lta[BM_ * 64];
  __shared__ alignas(16) s16 ltb[BN_ * 64];
  const int tid  = threadIdx.x;
  const int lane = tid & 63;
  const int wave = tid >> 6;
  const int wr = wave >> 1, wc = wave & 1;
  const int bm0 = (SX ? blockIdx.x : blockIdx.y) * BM_;
  const int bn0 = (SX ? blockIdx.y : blockIdx.x) * BN_;
  const int k0  = blockIdx.z * Kc;

  f32x4 acc[IM][JN];
  #pragma unroll
  for (int i = 0; i < IM; ++i)
    #pragma unroll
    for (int j = 0; j < JN; ++j)
      #pragma unroll
      for (int r = 0; r < 4; ++r) acc[i][j][r] = 0.0f;

  // staging: lane l -> row wave*8 + (l>>3), k-group ((l&7)^(l>>3)); LDS dest
  // linear (base + lane*16B), XOR lives in the global source address.
  const int lrow = lane >> 3;
  const int lke  = ((lane & 7) ^ lrow) * 8;
  const s16* Ab = A  + (size_t)(bm0 + wave * 8 + lrow) * K + k0 + lke;
  const s16* Bb = BT + (size_t)(bn0 + wave * 8 + lrow) * K + k0 + lke;

  const int fr = lane & 15;
  const int k8 = (lane >> 4) * 8;
  const int sw = (fr & 7) * 8;       // read-side XOR: row&7 == fr&7

  const int nt = Kc / 64;
  for (int t = 0; t < nt; ++t) {
    const int ko = t * 64;
    #pragma unroll
    for (int s = 0; s < SWA; ++s)
      gload_lds16(Ab + (size_t)s * 32 * K + ko, &lta[s * 2048 + wave * 512]);
    #pragma unroll
    for (int s = 0; s < SWB; ++s)
      gload_lds16(Bb + (size_t)s * 32 * K + ko, &ltb[s * 2048 + wave * 512]);
    __syncthreads();   // drains vmcnt(0): tile fully staged

    short8 af[2][IM], bfv[2][JN];
    #pragma unroll
    for (int kk = 0; kk < 2; ++kk) {
      #pragma unroll
      for (int i = 0; i < IM; ++i)
        af[kk][i] = *(const short8*)&lta[(wr * WM + i * 16 + fr) * 64 + ((kk * 32 + k8) ^ sw)];
      #pragma unroll
      for (int j = 0; j < JN; ++j)
        bfv[kk][j] = *(const short8*)&ltb[(wc * WN + j * 16 + fr) * 64 + ((kk * 32 + k8) ^ sw)];
    }
    #pragma unroll
    for (int kk = 0; kk < 2; ++kk)
      #pragma unroll
      for (int i = 0; i < IM; ++i)
        #pragma unroll
        for (int j = 0; j < JN; ++j)
          acc[i][j] = __builtin_amdgcn_mfma_f32_16x16x32_bf16(af[kk][i], bfv[kk][j], acc[i][j], 0, 0, 0);
    __syncthreads();   // all waves done reading before next tile overwrites
  }

  // epilogue — C/D layout: col = lane&15, row = (lane>>4)*4 + reg
  float* Cz = C ? C + (size_t)blockIdx.z * M * N : nullptr;
  const int r0 = (lane >> 4) * 4;
  const int cl = lane & 15;
  #pragma unroll
  for (int i = 0; i < IM; ++i) {
    const int gm = bm0 + wr * WM + i * 16 + r0;
    #pragma unroll
    for (int j = 0; j < JN; ++j) {
      const int gn = bn0 + wc * WN + j * 16 + cl;
      #pragma unroll
      for (int r = 0; r < 4; ++r) {
        const size_t idx = (size_t)(gm + r) * N + gn;
        float v = acc[i][j][r];
        if (rowscale) v *= rowscale[gm + r];
        if (addend)   v += addend[idx];
        if (Cz)    Cz[idx] = v;
        if (obf_n) obf_n[idx] = f2bf(v);
        if (obf_t) obf_t[(size_t)gn * M + (gm + r)] = f2bf(v);
      }
    }
  }
}

// ------- combine (KS=4): v = sum of 4 slices; fp32 + optional bf16 out -------
__global__ void __launch_bounds__(256)
k_combine4(const float* __restrict__ parts, size_t MN,
           float* __restrict__ C, s16* __restrict__ obf_n)
{
  const size_t i4 = ((size_t)blockIdx.x * 256 + threadIdx.x) * 4;
  if (i4 >= MN) return;
  f32x4 a = *(const f32x4*)(parts + i4);
  f32x4 b = *(const f32x4*)(parts + MN + i4);
  f32x4 c = *(const f32x4*)(parts + 2 * MN + i4);
  f32x4 d = *(const f32x4*)(parts + 3 * MN + i4);
  f32x4 v;
  #pragma unroll
  for (int r = 0; r < 4; ++r) v[r] = (a[r] + b[r]) + (c[r] + d[r]);
  if (C) *(f32x4*)(C + i4) = v;
  if (obf_n) {
    short4v o;
    #pragma unroll
    for (int r = 0; r < 4; ++r) o[r] = f2bf(v[r]);
    *(short4v*)(obf_n + i4) = o;
  }
}

// ------- fp32 -> bf16 convert, plain and/or transposed (64x64 tiles) ---------
__global__ void __launch_bounds__(256)
k_cvt_dual(const float* __restrict__ in, s16* __restrict__ outp, s16* __restrict__ outt,
           int R, int C)
{
  __shared__ float t[64][65];
  const int bx = blockIdx.x * 64, by = blockIdx.y * 64;
  const int tx = threadIdx.x & 63, ty = threadIdx.x >> 6;
  #pragma unroll
  for (int rr = 0; rr < 16; ++rr) {
    const int r = ty * 16 + rr;
    const float v = in[(size_t)(by + r) * C + bx + tx];
    t[r][tx] = v;
    if (outp) outp[(size_t)(by + r) * C + bx + tx] = f2bf(v);
  }
  if (outt) {
    __syncthreads();
    #pragma unroll
    for (int rr = 0; rr < 16; ++rr) {
      const int c = ty * 16 + rr;
      outt[(size_t)(bx + c) * R + by + tx] = f2bf(t[tx][c]);
    }
  }
}

// ------- Frobenius norm (deterministic two-stage) ----------------------------
__global__ void __launch_bounds__(256)
k_frob(const float* __restrict__ M_, float* __restrict__ partial, int m)
{
  const int row = blockIdx.x;
  float s = 0.f;
  for (int c = threadIdx.x; c < m; c += 256) {
    const float v = M_[(size_t)row * m + c];
    s += v * v;
  }
  __shared__ float red[256];
  red[threadIdx.x] = s; __syncthreads();
  for (int o = 128; o > 0; o >>= 1) {
    if (threadIdx.x < o) red[threadIdx.x] += red[threadIdx.x + o];
    __syncthreads();
  }
  if (threadIdx.x == 0) partial[row] = red[0];
}

__global__ void __launch_bounds__(256)
k_norm_fin(const float* __restrict__ partial, float* __restrict__ rnorm, int m)
{
  float s = 0.f;
  for (int i = threadIdx.x; i < m; i += 256) s += partial[i];
  __shared__ float red[256];
  red[threadIdx.x] = s; __syncthreads();
  for (int o = 128; o > 0; o >>= 1) {
    if (threadIdx.x < o) red[threadIdx.x] += red[threadIdx.x + o];
    __syncthreads();
  }
  if (threadIdx.x == 0) rnorm[0] = 1.0f / (sqrtf(red[0]) + 1e-12f);
}

__global__ void __launch_bounds__(256)
k_scale_g(const float* __restrict__ FtF, const float* __restrict__ rnorm,
          s16* __restrict__ g0, int total)
{
  const int i = blockIdx.x * 256 + threadIdx.x;
  if (i < total) g0[i] = f2bf(FtF[i] * rnorm[0]);
}

// s[k][j] = (gamma * lamS_j)^(2^k), k = 0..2  (row scales of the St chain)
__global__ void __launch_bounds__(256)
k_colscale(const float* __restrict__ lam, float* __restrict__ s, int n)
{
  const int j = blockIdx.x * 256 + threadIdx.x;
  if (j < n) {
    float v = 0.8f * lam[j];
    #pragma unroll
    for (int k = 0; k < 3; ++k) { s[(size_t)k * n + j] = v; v = v * v; }
  }
}

// ---------------- driver ----------------
extern "C" void kernel_launch(void* const* d_in, const int* in_sizes, int n_in,
                              void* d_out, int out_size, void* d_ws, size_t ws_size,
                              hipStream_t stream)
{
  const float* X   = (const float*)d_in[0];   // (m, n)
  const float* F   = (const float*)d_in[1];   // (m, m)
  const float* Q   = (const float*)d_in[2];   // (n, n)
  const float* lam = (const float*)d_in[3];   // (n,)

  int m = 1;
  while ((long long)m * m < (long long)in_sizes[1]) ++m;   // 512
  const int n = in_sizes[0] / m;                           // 4096
  const size_t MN = (size_t)m * n;                         // 2M elements

  char* w = (char*)d_ws;
  auto take = [&](size_t bytes) -> void* {
    char* p = w;
    w += (bytes + 255) & ~(size_t)255;
    return (void*)p;
  };

  // No overlays — ~119 MB total, ws is ~256 MB (fill evidence round 3).
  s16*   Qbf  = (s16*)take((size_t)n * n * 2);   // Q        (bf16)
  s16*   QTbf = (s16*)take((size_t)n * n * 2);   // Q^T      (bf16)
  s16*   Xbf  = (s16*)take(MN * 2);              // X        (bf16 plain)
  s16*   FTbf = (s16*)take((size_t)m * m * 2);   // F^T
  s16*   g[3];
  for (int k = 0; k < 3; ++k) g[k] = (s16*)take((size_t)m * m * 2);  // gF^(2^k)
  float* FtF  = (float*)take((size_t)m * m * 4);
  float* scal = (float*)take((size_t)3 * n * 4);
  float* part = (float*)take((size_t)m * 4);
  float* rno  = (float*)take(256);
  float* Zt   = (float*)take(MN * 4);            // running St fp32 (n x m)
  s16*   Sb0  = (s16*)take(MN * 2);              // St bf16 ping
  s16*   Sb1  = (s16*)take(MN * 2);              // St bf16 pong / S plain
  float* parts4 = (float*)take(4 * MN * 4);      // KS=4 fp32 partial slices
  (void)ws_size; (void)n_in; (void)out_size;

  s16* Splain = Sb1;   // Sb1 dead after doubling k=1 consumed it

  const int KS = 4;
  const dim3 blk(256);

  // 1) conversions (Q: single pass producing both layouts)
  k_cvt_dual<<<dim3(n / 64, m / 64), blk, 0, stream>>>(X, Xbf, nullptr, m, n);
  k_cvt_dual<<<dim3(n / 64, n / 64), blk, 0, stream>>>(Q, Qbf, QTbf, n, n);
  k_cvt_dual<<<dim3(m / 64, m / 64), blk, 0, stream>>>(F, nullptr, FTbf, m, m);

  // 2) FtF = F^T F  (A = F^T, BT = F^T => B = F)
  gemm_t<64, 64, false><<<dim3(m / 64, m / 64, 1), blk, 0, stream>>>(
      FTbf, FTbf, FtF, m, m, m, m, nullptr, nullptr, nullptr, nullptr);

  // 3) 1/(||FtF||_F + eps); g0 = bf16(FtF * rnorm)
  k_frob<<<dim3(m), blk, 0, stream>>>(FtF, part, m);
  k_norm_fin<<<dim3(1), blk, 0, stream>>>(part, rno, m);
  k_scale_g<<<dim3((m * m + 255) / 256), blk, 0, stream>>>(FtF, rno, g[0], m * m);

  // 4) squarings: g[k+1] = bf16(g[k] @ g[k])  (exactly symmetric each step)
  for (int k = 0; k < 2; ++k)
    gemm_t<64, 64, false><<<dim3(m / 64, m / 64, 1), blk, 0, stream>>>(
        g[k], g[k], nullptr, m, m, m, m, nullptr, nullptr, g[k + 1], nullptr);

  // 5) row scales (gamma*lam)^(2^k), k=0..2
  k_colscale<<<dim3((n + 255) / 256), blk, 0, stream>>>(lam, scal, n);

  // 6) St0 = Q^T X^T  (A = Q^T [big, -> blockIdx.x], BT = X), M=n, N=m, K=n,
  //    KS=4 -> 1024 blocks; combine -> Zt fp32 + Sb0 bf16
  gemm_t<128, 64, true><<<dim3(n / 128, m / 64, KS), blk, 0, stream>>>(
      QTbf, Xbf, parts4, n, m, n, n / KS, nullptr, nullptr, nullptr, nullptr);
  k_combine4<<<dim3((unsigned)(MN / 1024)), blk, 0, stream>>>(parts4, MN, Zt, Sb0);

  // 7) doublings (transposed): St_{k+1} = St_k + rs_k . (St_k @ g_k)
  //    A = St_k [big, -> blockIdx.x], BT = g_k (symmetric). Direct epilogue.
  gemm_t<64, 64, true><<<dim3(n / 64, m / 64, 1), blk, 0, stream>>>(
      Sb0, g[0], Zt, n, m, m, m, scal + 0 * (size_t)n, Zt, Sb1, nullptr);
  gemm_t<64, 64, true><<<dim3(n / 64, m / 64, 1), blk, 0, stream>>>(
      Sb1, g[1], Zt, n, m, m, m, scal + 1 * (size_t)n, Zt, Sb0, nullptr);
  // last: emit only S plain (m x n) via transposed bf16 write
  gemm_t<64, 64, true><<<dim3(n / 64, m / 64, 1), blk, 0, stream>>>(
      Sb0, g[2], nullptr, n, m, m, m, scal + 2 * (size_t)n, Zt, nullptr, Splain);

  // 8) Z = S @ Q^T  (A = S plain, BT = Q [big, already blockIdx.x]), KS=4
  gemm_t<64, 128, false><<<dim3(n / 128, m / 64, KS), blk, 0, stream>>>(
      Splain, Qbf, parts4, m, n, n, n / KS, nullptr, nullptr, nullptr, nullptr);
  k_combine4<<<dim3((unsigned)(MN / 1024)), blk, 0, stream>>>(parts4, MN, (float*)d_out, nullptr);
}

// Round 6
// 158.111 us; speedup vs baseline: 3.1872x; 1.1687x over previous
//
#include <hip/hip_runtime.h>
#include <stdint.h>

typedef short s16;
typedef __attribute__((ext_vector_type(8))) short short8;  // 8 bf16 (4 VGPRs)
typedef __attribute__((ext_vector_type(4))) float f32x4;
typedef __attribute__((ext_vector_type(4))) short short4v;

__device__ __forceinline__ s16 f2bf(float f) {
  union { float f; uint32_t u; } v; v.f = f;
  uint32_t u = v.u;
  uint32_t r = (u + 0x7fffu + ((u >> 16) & 1u)) >> 16;  // RNE
  return (s16)(uint16_t)r;
}

#define GLOBAL_AS __attribute__((address_space(1)))
#define LDS_AS    __attribute__((address_space(3)))
__device__ __forceinline__ void gload_lds16(const void* g, void* l) {
  __builtin_amdgcn_global_load_lds((const GLOBAL_AS uint32_t*)g, (LDS_AS uint32_t*)l, 16, 0, 0);
}

// ---------------- GEMM: C(MxN) = A(MxK,row) @ B, B given as BT(NxK,row) -------
// Proven single-buffer 2-barrier K-loop, BK=64, XOR-swizzled LDS via
// pre-swizzled global source (linear LDS dest; same involution on read).
// SX: blockIdx.x indexes the M(A) direction if true, else N(BT). Pick SX so
// blockIdx.x walks the LARGE operand's panels (XCD = id % 8 L2 locality).
// gridDim.z>1: K-split, z writes C + z*M*N fp32 partials, epilogue extras null.
// gridDim.z==1: fused epilogue v = acc*rowscale[row] + addend[idx];
//   C[idx]=v; obf_n[idx]=bf16(v); obf_t[col*M+row]=bf16(v).
template<int BM_, int BN_, bool SX>
__global__ void __launch_bounds__(256, 2)
gemm_t(const s16* __restrict__ A, const s16* __restrict__ BT,
       float* C, int M, int N, int K, int Kc,
       const float* __restrict__ rowscale,
       const float* addend,            // may alias C (in-place); no restrict
       s16* __restrict__ obf_n, s16* __restrict__ obf_t)
{
  constexpr int SWA = BM_ / 32;       // staging sweeps (32 rows x 64k each)
  constexpr int SWB = BN_ / 32;
  constexpr int WM  = BM_ / 2;        // per-wave tile (2x2 wave grid)
  constexpr int WN  = BN_ / 2;
  constexpr int IM  = WM / 16;
  constexpr int JN  = WN / 16;

  __shared__ alignas(16) s16 lta[BM_ * 64];
  __shared__ alignas(16) s16 ltb[BN_ * 64];
  const int tid  = threadIdx.x;
  const int lane = tid & 63;
  const int wave = tid >> 6;
  const int wr = wave >> 1, wc = wave & 1;
  const int bm0 = (SX ? blockIdx.x : blockIdx.y) * BM_;
  const int bn0 = (SX ? blockIdx.y : blockIdx.x) * BN_;
  const int k0  = blockIdx.z * Kc;

  f32x4 acc[IM][JN];
  #pragma unroll
  for (int i = 0; i < IM; ++i)
    #pragma unroll
    for (int j = 0; j < JN; ++j)
      #pragma unroll
      for (int r = 0; r < 4; ++r) acc[i][j][r] = 0.0f;

  const int lrow = lane >> 3;
  const int lke  = ((lane & 7) ^ lrow) * 8;
  const s16* Ab = A  + (size_t)(bm0 + wave * 8 + lrow) * K + k0 + lke;
  const s16* Bb = BT + (size_t)(bn0 + wave * 8 + lrow) * K + k0 + lke;

  const int fr = lane & 15;
  const int k8 = (lane >> 4) * 8;
  const int sw = (fr & 7) * 8;       // read-side XOR: row&7 == fr&7

  const int nt = Kc / 64;
  for (int t = 0; t < nt; ++t) {
    const int ko = t * 64;
    #pragma unroll
    for (int s = 0; s < SWA; ++s)
      gload_lds16(Ab + (size_t)s * 32 * K + ko, &lta[s * 2048 + wave * 512]);
    #pragma unroll
    for (int s = 0; s < SWB; ++s)
      gload_lds16(Bb + (size_t)s * 32 * K + ko, &ltb[s * 2048 + wave * 512]);
    __syncthreads();   // drains vmcnt(0): tile fully staged

    short8 af[2][IM], bfv[2][JN];
    #pragma unroll
    for (int kk = 0; kk < 2; ++kk) {
      #pragma unroll
      for (int i = 0; i < IM; ++i)
        af[kk][i] = *(const short8*)&lta[(wr * WM + i * 16 + fr) * 64 + ((kk * 32 + k8) ^ sw)];
      #pragma unroll
      for (int j = 0; j < JN; ++j)
        bfv[kk][j] = *(const short8*)&ltb[(wc * WN + j * 16 + fr) * 64 + ((kk * 32 + k8) ^ sw)];
    }
    #pragma unroll
    for (int kk = 0; kk < 2; ++kk)
      #pragma unroll
      for (int i = 0; i < IM; ++i)
        #pragma unroll
        for (int j = 0; j < JN; ++j)
          acc[i][j] = __builtin_amdgcn_mfma_f32_16x16x32_bf16(af[kk][i], bfv[kk][j], acc[i][j], 0, 0, 0);
    __syncthreads();   // all waves done reading before next tile overwrites
  }

  // epilogue — C/D layout: col = lane&15, row = (lane>>4)*4 + reg
  float* Cz = C ? C + (size_t)blockIdx.z * M * N : nullptr;
  const int r0 = (lane >> 4) * 4;
  const int cl = lane & 15;
  #pragma unroll
  for (int i = 0; i < IM; ++i) {
    const int gm = bm0 + wr * WM + i * 16 + r0;
    #pragma unroll
    for (int j = 0; j < JN; ++j) {
      const int gn = bn0 + wc * WN + j * 16 + cl;
      #pragma unroll
      for (int r = 0; r < 4; ++r) {
        const size_t idx = (size_t)(gm + r) * N + gn;
        float v = acc[i][j][r];
        if (rowscale) v *= rowscale[gm + r];
        if (addend)   v += addend[idx];
        if (Cz)    Cz[idx] = v;
        if (obf_n) obf_n[idx] = f2bf(v);
        if (obf_t) obf_t[(size_t)gn * M + (gm + r)] = f2bf(v);
      }
    }
  }
}

// ------- combine (KS=4): v = sum of 4 slices; fp32 and/or bf16 out -----------
__global__ void __launch_bounds__(256)
k_combine4(const float* __restrict__ parts, size_t MN,
           float* __restrict__ C, s16* __restrict__ obf_n)
{
  const size_t i4 = ((size_t)blockIdx.x * 256 + threadIdx.x) * 4;
  if (i4 >= MN) return;
  f32x4 a = *(const f32x4*)(parts + i4);
  f32x4 b = *(const f32x4*)(parts + MN + i4);
  f32x4 c = *(const f32x4*)(parts + 2 * MN + i4);
  f32x4 d = *(const f32x4*)(parts + 3 * MN + i4);
  f32x4 v;
  #pragma unroll
  for (int r = 0; r < 4; ++r) v[r] = (a[r] + b[r]) + (c[r] + d[r]);
  if (C) *(f32x4*)(C + i4) = v;
  if (obf_n) {
    short4v o;
    #pragma unroll
    for (int r = 0; r < 4; ++r) o[r] = f2bf(v[r]);
    *(short4v*)(obf_n + i4) = o;
  }
}

// ------- fp32 -> bf16 convert, vectorized: plain and/or transposed -----------
// 64x64 tiles; float4 reads (256B/row runs), short4 plain writes, fp32 LDS
// [64][65] transpose (2 lanes/bank both phases = conflict-free), short4
// transposed writes (128B runs).
__global__ void __launch_bounds__(256)
k_cvt_v(const float* __restrict__ in, s16* __restrict__ outp, s16* __restrict__ outt,
        int R, int C)
{
  __shared__ float t[64][65];
  const int bx = blockIdx.x * 64, by = blockIdx.y * 64;
  const int r0 = threadIdx.x >> 4;         // 0..15
  const int c4 = (threadIdx.x & 15) * 4;   // 0..60
  #pragma unroll
  for (int rr = 0; rr < 4; ++rr) {
    const int r = rr * 16 + r0;
    const f32x4 v = *(const f32x4*)(in + (size_t)(by + r) * C + bx + c4);
    if (outp) {
      short4v o;
      #pragma unroll
      for (int j = 0; j < 4; ++j) o[j] = f2bf(v[j]);
      *(short4v*)(outp + (size_t)(by + r) * C + bx + c4) = o;
    }
    if (outt) {
      t[r][c4] = v[0]; t[r][c4 + 1] = v[1]; t[r][c4 + 2] = v[2]; t[r][c4 + 3] = v[3];
    }
  }
  if (outt) {
    __syncthreads();
    const int cc = threadIdx.x >> 4;       // out-row within tile
    const int r4 = (threadIdx.x & 15) * 4;
    #pragma unroll
    for (int p = 0; p < 4; ++p) {
      const int c = p * 16 + cc;
      short4v o;
      #pragma unroll
      for (int j = 0; j < 4; ++j) o[j] = f2bf(t[r4 + j][c]);
      *(short4v*)(outt + (size_t)(bx + c) * R + by + r4) = o;
    }
  }
}

// ------- Frobenius norm (deterministic two-stage) ----------------------------
__global__ void __launch_bounds__(256)
k_frob(const float* __restrict__ M_, float* __restrict__ partial, int m)
{
  const int row = blockIdx.x;
  float s = 0.f;
  for (int c = threadIdx.x; c < m; c += 256) {
    const float v = M_[(size_t)row * m + c];
    s += v * v;
  }
  __shared__ float red[256];
  red[threadIdx.x] = s; __syncthreads();
  for (int o = 128; o > 0; o >>= 1) {
    if (threadIdx.x < o) red[threadIdx.x] += red[threadIdx.x + o];
    __syncthreads();
  }
  if (threadIdx.x == 0) partial[row] = red[0];
}

__global__ void __launch_bounds__(256)
k_norm_fin(const float* __restrict__ partial, float* __restrict__ rnorm, int m)
{
  float s = 0.f;
  for (int i = threadIdx.x; i < m; i += 256) s += partial[i];
  __shared__ float red[256];
  red[threadIdx.x] = s; __syncthreads();
  for (int o = 128; o > 0; o >>= 1) {
    if (threadIdx.x < o) red[threadIdx.x] += red[threadIdx.x + o];
    __syncthreads();
  }
  if (threadIdx.x == 0) rnorm[0] = 1.0f / (sqrtf(red[0]) + 1e-12f);
}

__global__ void __launch_bounds__(256)
k_scale_g(const float* __restrict__ FtF, const float* __restrict__ rnorm,
          s16* __restrict__ g0, int total)
{
  const int i = blockIdx.x * 256 + threadIdx.x;
  if (i < total) g0[i] = f2bf(FtF[i] * rnorm[0]);
}

// s[k][j] = (gamma * lamS_j)^(2^k), k = 0..1  (row scales of the St chain)
__global__ void __launch_bounds__(256)
k_colscale(const float* __restrict__ lam, float* __restrict__ s, int n)
{
  const int j = blockIdx.x * 256 + threadIdx.x;
  if (j < n) {
    float v = 0.8f * lam[j];
    #pragma unroll
    for (int k = 0; k < 2; ++k) { s[(size_t)k * n + j] = v; v = v * v; }
  }
}

// ---------------- driver ----------------
extern "C" void kernel_launch(void* const* d_in, const int* in_sizes, int n_in,
                              void* d_out, int out_size, void* d_ws, size_t ws_size,
                              hipStream_t stream)
{
  const float* X   = (const float*)d_in[0];   // (m, n)
  const float* F   = (const float*)d_in[1];   // (m, m)
  const float* Q   = (const float*)d_in[2];   // (n, n)
  const float* lam = (const float*)d_in[3];   // (n,)

  int m = 1;
  while ((long long)m * m < (long long)in_sizes[1]) ++m;   // 512
  const int n = in_sizes[0] / m;                           // 4096
  const size_t MN = (size_t)m * n;                         // 2M elements
  const size_t MM = (size_t)m * m;

  char* w = (char*)d_ws;
  auto take = [&](size_t bytes) -> void* {
    char* p = w;
    w += (bytes + 255) & ~(size_t)255;
    return (void*)p;
  };

  // ~119 MB total; ws is ~256 MB (fill evidence round 3). No overlays.
  s16*   Qbf  = (s16*)take((size_t)n * n * 2);   // Q        (bf16)
  s16*   QTbf = (s16*)take((size_t)n * n * 2);   // Q^T      (bf16)
  s16*   Xbf  = (s16*)take(MN * 2);              // X        (bf16 plain)
  s16*   FTbf = (s16*)take(MM * 2);              // F^T
  s16*   g[2];
  for (int k = 0; k < 2; ++k) g[k] = (s16*)take(MM * 2);   // gF, gF^2
  float* FtF  = (float*)take(MM * 4);
  float* scal = (float*)take((size_t)2 * n * 4);
  float* part = (float*)take((size_t)m * 4);
  float* rno  = (float*)take(256);
  float* Zt   = (float*)take(MN * 4);            // running St fp32 (n x m)
  s16*   Sb0  = (s16*)take(MN * 2);              // St bf16 ping
  s16*   Sb1  = (s16*)take(MN * 2);              // St bf16 pong
  float* parts4 = (float*)take(4 * MN * 4);      // KS=4 fp32 partial slices
  (void)ws_size; (void)n_in; (void)out_size;

  s16* Splain = Sb0;   // Sb0 dead after doubling k=0 consumed it

  const int KS = 4;
  const dim3 blk(256);

  // 1) conversions (vectorized)
  k_cvt_v<<<dim3(n / 64, m / 64), blk, 0, stream>>>(X, Xbf, nullptr, m, n);
  k_cvt_v<<<dim3(n / 64, n / 64), blk, 0, stream>>>(Q, Qbf, QTbf, n, n);
  k_cvt_v<<<dim3(m / 64, m / 64), blk, 0, stream>>>(F, nullptr, FTbf, m, m);

  // 2) FtF = F^T F  (A = F^T, BT = F^T => B = F), KS=4 -> 256 blocks
  gemm_t<64, 64, false><<<dim3(m / 64, m / 64, KS), blk, 0, stream>>>(
      FTbf, FTbf, parts4, m, m, m, m / KS, nullptr, nullptr, nullptr, nullptr);
  k_combine4<<<dim3((unsigned)(MM / 1024)), blk, 0, stream>>>(parts4, MM, FtF, nullptr);

  // 3) 1/(||FtF||_F + eps); g0 = bf16(FtF * rnorm)
  k_frob<<<dim3(m), blk, 0, stream>>>(FtF, part, m);
  k_norm_fin<<<dim3(1), blk, 0, stream>>>(part, rno, m);
  k_scale_g<<<dim3((m * m + 255) / 256), blk, 0, stream>>>(FtF, rno, g[0], m * m);

  // 4) one squaring: g1 = bf16(g0 @ g0)  (symmetric), KS=4
  gemm_t<64, 64, false><<<dim3(m / 64, m / 64, KS), blk, 0, stream>>>(
      g[0], g[0], parts4, m, m, m, m / KS, nullptr, nullptr, nullptr, nullptr);
  k_combine4<<<dim3((unsigned)(MM / 1024)), blk, 0, stream>>>(parts4, MM, nullptr, g[1]);

  // 5) row scales (gamma*lam)^(2^k), k=0..1
  k_colscale<<<dim3((n + 255) / 256), blk, 0, stream>>>(lam, scal, n);

  // 6) St0 = Q^T X^T  (A = Q^T [big -> blockIdx.x], BT = X), KS=4
  gemm_t<128, 64, true><<<dim3(n / 128, m / 64, KS), blk, 0, stream>>>(
      QTbf, Xbf, parts4, n, m, n, n / KS, nullptr, nullptr, nullptr, nullptr);
  k_combine4<<<dim3((unsigned)(MN / 1024)), blk, 0, stream>>>(parts4, MN, Zt, Sb0);

  // 7) 2 doublings (4 Neumann terms; rho ~ 0.1 -> trunc ~ 2.4e-3):
  //    St_{k+1} = St_k + rs_k . (St_k @ g_k)
  gemm_t<64, 64, true><<<dim3(n / 64, m / 64, 1), blk, 0, stream>>>(
      Sb0, g[0], Zt, n, m, m, m, scal + 0 * (size_t)n, Zt, Sb1, nullptr);
  // last: emit only S plain (m x n) via transposed bf16 write
  gemm_t<64, 64, true><<<dim3(n / 64, m / 64, 1), blk, 0, stream>>>(
      Sb1, g[1], nullptr, n, m, m, m, scal + 1 * (size_t)n, Zt, nullptr, Splain);

  // 8) Z = S @ Q^T  (A = S plain, BT = Q [big -> blockIdx.x]), KS=4
  gemm_t<64, 128, false><<<dim3(n / 128, m / 64, KS), blk, 0, stream>>>(
      Splain, Qbf, parts4, m, n, n, n / KS, nullptr, nullptr, nullptr, nullptr);
  k_combine4<<<dim3((unsigned)(MN / 1024)), blk, 0, stream>>>(parts4, MN, (float*)d_out, nullptr);
}

// Round 7
// 139.462 us; speedup vs baseline: 3.6134x; 1.1337x over previous
//
#include <hip/hip_runtime.h>
#include <stdint.h>

typedef short s16;
typedef __attribute__((ext_vector_type(8))) short short8;  // 8 bf16 (4 VGPRs)
typedef __attribute__((ext_vector_type(4))) float f32x4;
typedef __attribute__((ext_vector_type(4))) short short4v;

__device__ __forceinline__ s16 f2bf(float f) {
  union { float f; uint32_t u; } v; v.f = f;
  uint32_t u = v.u;
  uint32_t r = (u + 0x7fffu + ((u >> 16) & 1u)) >> 16;  // RNE
  return (s16)(uint16_t)r;
}
__device__ __forceinline__ float bf2f(s16 b) {
  union { uint32_t u; float f; } v; v.u = ((uint32_t)(uint16_t)b) << 16;
  return v.f;
}

#define GLOBAL_AS __attribute__((address_space(1)))
#define LDS_AS    __attribute__((address_space(3)))
__device__ __forceinline__ void gload_lds16(const void* g, void* l) {
  __builtin_amdgcn_global_load_lds((const GLOBAL_AS uint32_t*)g, (LDS_AS uint32_t*)l, 16, 0, 0);
}

// ---------------- GEMM: C(MxN) = A(MxK,row) @ B, B given as BT(NxK,row) -------
// Proven single-buffer 2-barrier K-loop, BK=64, XOR-swizzled LDS via
// pre-swizzled global source (linear LDS dest; same involution on read).
// SX: blockIdx.x indexes M(A) if true else N(BT); pick so blockIdx.x walks the
// LARGE operand (XCD = id%8 L2 locality).
// All outputs are bf16:
//   gridDim.z>1 : obf_n + z*M*N gets raw bf16 partials (rowscale/addend null).
//   gridDim.z==1: v = acc*rowscale[row] + bf2f(addend_bf[idx]);
//                 obf_n[idx]=bf16(v); obf_t[col*M+row]=bf16(v).
template<int BM_, int BN_, bool SX>
__global__ void __launch_bounds__(256, 2)
gemm_t(const s16* __restrict__ A, const s16* __restrict__ BT,
       int M, int N, int K, int Kc,
       const float* __restrict__ rowscale,
       const s16* __restrict__ addend_bf,
       s16* __restrict__ obf_n, s16* __restrict__ obf_t)
{
  constexpr int SWA = BM_ / 32;       // staging sweeps (32 rows x 64k each)
  constexpr int SWB = BN_ / 32;
  constexpr int WM  = BM_ / 2;        // per-wave tile (2x2 wave grid)
  constexpr int WN  = BN_ / 2;
  constexpr int IM  = WM / 16;
  constexpr int JN  = WN / 16;

  __shared__ alignas(16) s16 lta[BM_ * 64];
  __shared__ alignas(16) s16 ltb[BN_ * 64];
  const int tid  = threadIdx.x;
  const int lane = tid & 63;
  const int wave = tid >> 6;
  const int wr = wave >> 1, wc = wave & 1;
  const int bm0 = (SX ? blockIdx.x : blockIdx.y) * BM_;
  const int bn0 = (SX ? blockIdx.y : blockIdx.x) * BN_;
  const int k0  = blockIdx.z * Kc;

  f32x4 acc[IM][JN];
  #pragma unroll
  for (int i = 0; i < IM; ++i)
    #pragma unroll
    for (int j = 0; j < JN; ++j)
      #pragma unroll
      for (int r = 0; r < 4; ++r) acc[i][j][r] = 0.0f;

  const int lrow = lane >> 3;
  const int lke  = ((lane & 7) ^ lrow) * 8;
  const s16* Ab = A  + (size_t)(bm0 + wave * 8 + lrow) * K + k0 + lke;
  const s16* Bb = BT + (size_t)(bn0 + wave * 8 + lrow) * K + k0 + lke;

  const int fr = lane & 15;
  const int k8 = (lane >> 4) * 8;
  const int sw = (fr & 7) * 8;       // read-side XOR: row&7 == fr&7

  const int nt = Kc / 64;
  for (int t = 0; t < nt; ++t) {
    const int ko = t * 64;
    #pragma unroll
    for (int s = 0; s < SWA; ++s)
      gload_lds16(Ab + (size_t)s * 32 * K + ko, &lta[s * 2048 + wave * 512]);
    #pragma unroll
    for (int s = 0; s < SWB; ++s)
      gload_lds16(Bb + (size_t)s * 32 * K + ko, &ltb[s * 2048 + wave * 512]);
    __syncthreads();   // drains vmcnt(0): tile fully staged

    short8 af[2][IM], bfv[2][JN];
    #pragma unroll
    for (int kk = 0; kk < 2; ++kk) {
      #pragma unroll
      for (int i = 0; i < IM; ++i)
        af[kk][i] = *(const short8*)&lta[(wr * WM + i * 16 + fr) * 64 + ((kk * 32 + k8) ^ sw)];
      #pragma unroll
      for (int j = 0; j < JN; ++j)
        bfv[kk][j] = *(const short8*)&ltb[(wc * WN + j * 16 + fr) * 64 + ((kk * 32 + k8) ^ sw)];
    }
    #pragma unroll
    for (int kk = 0; kk < 2; ++kk)
      #pragma unroll
      for (int i = 0; i < IM; ++i)
        #pragma unroll
        for (int j = 0; j < JN; ++j)
          acc[i][j] = __builtin_amdgcn_mfma_f32_16x16x32_bf16(af[kk][i], bfv[kk][j], acc[i][j], 0, 0, 0);
    __syncthreads();   // all waves done reading before next tile overwrites
  }

  // epilogue — C/D layout: col = lane&15, row = (lane>>4)*4 + reg
  s16* on = obf_n ? obf_n + (size_t)blockIdx.z * M * N : nullptr;
  const int r0 = (lane >> 4) * 4;
  const int cl = lane & 15;
  #pragma unroll
  for (int i = 0; i < IM; ++i) {
    const int gm = bm0 + wr * WM + i * 16 + r0;
    #pragma unroll
    for (int j = 0; j < JN; ++j) {
      const int gn = bn0 + wc * WN + j * 16 + cl;
      #pragma unroll
      for (int r = 0; r < 4; ++r) {
        const size_t idx = (size_t)(gm + r) * N + gn;
        float v = acc[i][j][r];
        if (rowscale)  v *= rowscale[gm + r];
        if (addend_bf) v += bf2f(addend_bf[idx]);
        if (on)    on[idx] = f2bf(v);
        if (obf_t) obf_t[(size_t)gn * M + (gm + r)] = f2bf(v);
      }
    }
  }
}

// ------- combine (KS=4, bf16 slices): fp32 and/or bf16 out -------------------
__global__ void __launch_bounds__(256)
k_combine4b(const s16* __restrict__ parts, size_t MN,
            float* __restrict__ Cf, s16* __restrict__ obf)
{
  const size_t i8 = ((size_t)blockIdx.x * 256 + threadIdx.x) * 8;
  if (i8 >= MN) return;
  short8 a = *(const short8*)(parts + i8);
  short8 b = *(const short8*)(parts + MN + i8);
  short8 c = *(const short8*)(parts + 2 * MN + i8);
  short8 d = *(const short8*)(parts + 3 * MN + i8);
  float v[8];
  #pragma unroll
  for (int r = 0; r < 8; ++r)
    v[r] = (bf2f(a[r]) + bf2f(b[r])) + (bf2f(c[r]) + bf2f(d[r]));
  if (Cf) {
    f32x4 lo, hi;
    #pragma unroll
    for (int r = 0; r < 4; ++r) { lo[r] = v[r]; hi[r] = v[r + 4]; }
    *(f32x4*)(Cf + i8) = lo;
    *(f32x4*)(Cf + i8 + 4) = hi;
  }
  if (obf) {
    short8 o;
    #pragma unroll
    for (int r = 0; r < 8; ++r) o[r] = f2bf(v[r]);
    *(short8*)(obf + i8) = o;
  }
}

// ------- fused combine + per-row Frobenius partial for FtF -------------------
// one block per row; sums 4 bf16 slices -> FtF fp32 row + partial[row]=sum(v^2)
__global__ void __launch_bounds__(256)
k_comb_frob(const s16* __restrict__ parts, int m,
            float* __restrict__ FtF, float* __restrict__ partial)
{
  const int row = blockIdx.x;
  const size_t MM = (size_t)m * m;
  float ss = 0.f;
  for (int c = threadIdx.x; c < m; c += 256) {
    const size_t idx = (size_t)row * m + c;
    float v = (bf2f(parts[idx]) + bf2f(parts[MM + idx]))
            + (bf2f(parts[2 * MM + idx]) + bf2f(parts[3 * MM + idx]));
    FtF[idx] = v;
    ss += v * v;
  }
  __shared__ float red[256];
  red[threadIdx.x] = ss; __syncthreads();
  for (int o = 128; o > 0; o >>= 1) {
    if (threadIdx.x < o) red[threadIdx.x] += red[threadIdx.x + o];
    __syncthreads();
  }
  if (threadIdx.x == 0) partial[row] = red[0];
}

__global__ void __launch_bounds__(256)
k_norm_fin(const float* __restrict__ partial, float* __restrict__ rnorm, int m)
{
  float s = 0.f;
  for (int i = threadIdx.x; i < m; i += 256) s += partial[i];
  __shared__ float red[256];
  red[threadIdx.x] = s; __syncthreads();
  for (int o = 128; o > 0; o >>= 1) {
    if (threadIdx.x < o) red[threadIdx.x] += red[threadIdx.x + o];
    __syncthreads();
  }
  if (threadIdx.x == 0) rnorm[0] = 1.0f / (sqrtf(red[0]) + 1e-12f);
}

__global__ void __launch_bounds__(256)
k_scale_g(const float* __restrict__ FtF, const float* __restrict__ rnorm,
          s16* __restrict__ g0, int total)
{
  const int i = blockIdx.x * 256 + threadIdx.x;
  if (i < total) g0[i] = f2bf(FtF[i] * rnorm[0]);
}

// s[k][j] = (gamma * lamS_j)^(2^k), k = 0..1  (row scales of the St chain)
__global__ void __launch_bounds__(256)
k_colscale(const float* __restrict__ lam, float* __restrict__ s, int n)
{
  const int j = blockIdx.x * 256 + threadIdx.x;
  if (j < n) {
    float v = 0.8f * lam[j];
    #pragma unroll
    for (int k = 0; k < 2; ++k) { s[(size_t)k * n + j] = v; v = v * v; }
  }
}

// ------- fp32 -> bf16 convert, vectorized: plain and/or transposed -----------
__global__ void __launch_bounds__(256)
k_cvt_v(const float* __restrict__ in, s16* __restrict__ outp, s16* __restrict__ outt,
        int R, int C)
{
  __shared__ float t[64][65];
  const int bx = blockIdx.x * 64, by = blockIdx.y * 64;
  const int r0 = threadIdx.x >> 4;         // 0..15
  const int c4 = (threadIdx.x & 15) * 4;   // 0..60
  #pragma unroll
  for (int rr = 0; rr < 4; ++rr) {
    const int r = rr * 16 + r0;
    const f32x4 v = *(const f32x4*)(in + (size_t)(by + r) * C + bx + c4);
    if (outp) {
      short4v o;
      #pragma unroll
      for (int j = 0; j < 4; ++j) o[j] = f2bf(v[j]);
      *(short4v*)(outp + (size_t)(by + r) * C + bx + c4) = o;
    }
    if (outt) {
      t[r][c4] = v[0]; t[r][c4 + 1] = v[1]; t[r][c4 + 2] = v[2]; t[r][c4 + 3] = v[3];
    }
  }
  if (outt) {
    __syncthreads();
    const int cc = threadIdx.x >> 4;
    const int r4 = (threadIdx.x & 15) * 4;
    #pragma unroll
    for (int p = 0; p < 4; ++p) {
      const int c = p * 16 + cc;
      short4v o;
      #pragma unroll
      for (int j = 0; j < 4; ++j) o[j] = f2bf(t[r4 + j][c]);
      *(short4v*)(outt + (size_t)(bx + c) * R + by + r4) = o;
    }
  }
}

// ---------------- driver ----------------
extern "C" void kernel_launch(void* const* d_in, const int* in_sizes, int n_in,
                              void* d_out, int out_size, void* d_ws, size_t ws_size,
                              hipStream_t stream)
{
  const float* X   = (const float*)d_in[0];   // (m, n)
  const float* F   = (const float*)d_in[1];   // (m, m)
  const float* Q   = (const float*)d_in[2];   // (n, n)
  const float* lam = (const float*)d_in[3];   // (n,)

  int m = 1;
  while ((long long)m * m < (long long)in_sizes[1]) ++m;   // 512
  const int n = in_sizes[0] / m;                           // 4096
  const size_t MN = (size_t)m * n;                         // 2M elements
  const size_t MM = (size_t)m * m;

  char* w = (char*)d_ws;
  auto take = [&](size_t bytes) -> void* {
    char* p = w;
    w += (bytes + 255) & ~(size_t)255;
    return (void*)p;
  };

  // ~99 MB total; ws ~256 MB (fill evidence). No overlays except Splain=Sb0.
  s16*   Qbf  = (s16*)take((size_t)n * n * 2);   // Q        (bf16)
  s16*   QTbf = (s16*)take((size_t)n * n * 2);   // Q^T      (bf16)
  s16*   Xbf  = (s16*)take(MN * 2);              // X        (bf16 plain)
  s16*   FTbf = (s16*)take(MM * 2);              // F^T
  s16*   g[2];
  for (int k = 0; k < 2; ++k) g[k] = (s16*)take(MM * 2);   // gF, gF^2
  float* FtF  = (float*)take(MM * 4);
  float* scal = (float*)take((size_t)2 * n * 4);
  float* part = (float*)take((size_t)m * 4);
  float* rno  = (float*)take(256);
  s16*   Sb0  = (s16*)take(MN * 2);              // St bf16 ping
  s16*   Sb1  = (s16*)take(MN * 2);              // St bf16 pong
  s16*   partsb = (s16*)take(4 * MN * 2);        // KS=4 bf16 partial slices
  (void)ws_size; (void)n_in; (void)out_size;

  s16* Splain = Sb0;   // Sb0 dead after doubling k=0 consumed it

  const int KS = 4;
  const dim3 blk(256);

  // 1) conversions (vectorized)
  k_cvt_v<<<dim3(n / 64, m / 64), blk, 0, stream>>>(X, Xbf, nullptr, m, n);
  k_cvt_v<<<dim3(n / 64, n / 64), blk, 0, stream>>>(Q, Qbf, QTbf, n, n);
  k_cvt_v<<<dim3(m / 64, m / 64), blk, 0, stream>>>(F, nullptr, FTbf, m, m);

  // 2) FtF = F^T F (A = F^T, BT = F^T => B = F), KS=4 bf16 partials
  gemm_t<64, 64, false><<<dim3(m / 64, m / 64, KS), blk, 0, stream>>>(
      FTbf, FTbf, m, m, m, m / KS, nullptr, nullptr, partsb, nullptr);
  // 3) fused combine + Frobenius partial; then 1/(norm+eps); g0 = bf16(FtF*rn)
  k_comb_frob<<<dim3(m), blk, 0, stream>>>(partsb, m, FtF, part);
  k_norm_fin<<<dim3(1), blk, 0, stream>>>(part, rno, m);
  k_scale_g<<<dim3((int)((MM + 255) / 256)), blk, 0, stream>>>(FtF, rno, g[0], (int)MM);

  // 4) one squaring: g1 = bf16(g0 @ g0) (symmetric), KS=4 bf16 partials
  gemm_t<64, 64, false><<<dim3(m / 64, m / 64, KS), blk, 0, stream>>>(
      g[0], g[0], m, m, m, m / KS, nullptr, nullptr, partsb, nullptr);
  k_combine4b<<<dim3((unsigned)(MM / 2048)), blk, 0, stream>>>(partsb, MM, nullptr, g[1]);

  // 5) row scales (gamma*lam)^(2^k), k=0..1
  k_colscale<<<dim3((n + 255) / 256), blk, 0, stream>>>(lam, scal, n);

  // 6) St0 = Q^T X^T  (A = Q^T [big -> blockIdx.x], BT = X), 128x128 KS=4
  gemm_t<128, 128, true><<<dim3(n / 128, m / 128, KS), blk, 0, stream>>>(
      QTbf, Xbf, n, m, n, n / KS, nullptr, nullptr, partsb, nullptr);
  k_combine4b<<<dim3((unsigned)(MN / 2048)), blk, 0, stream>>>(partsb, MN, nullptr, Sb0);

  // 7) 2 doublings (4 Neumann terms): St_{k+1} = St_k + rs_k.(St_k @ g_k)
  //    bf16 addend = the A operand buffer itself (read-only twice).
  gemm_t<64, 64, true><<<dim3(n / 64, m / 64, 1), blk, 0, stream>>>(
      Sb0, g[0], n, m, m, m, scal + 0 * (size_t)n, Sb0, Sb1, nullptr);
  // last: emit only S plain (m x n) via transposed bf16 write
  gemm_t<64, 64, true><<<dim3(n / 64, m / 64, 1), blk, 0, stream>>>(
      Sb1, g[1], n, m, m, m, scal + 1 * (size_t)n, Sb1, nullptr, Splain);

  // 8) Z = S @ Q^T  (A = S plain, BT = Q [big -> blockIdx.x]), 128x128 KS=4
  gemm_t<128, 128, false><<<dim3(n / 128, m / 128, KS), blk, 0, stream>>>(
      Splain, Qbf, m, n, n, n / KS, nullptr, nullptr, partsb, nullptr);
  k_combine4b<<<dim3((unsigned)(MN / 2048)), blk, 0, stream>>>(partsb, MN, (float*)d_out, nullptr);
}

// Round 8
// 135.149 us; speedup vs baseline: 3.7287x; 1.0319x over previous
//
#include <hip/hip_runtime.h>
#include <stdint.h>

typedef short s16;
typedef __attribute__((ext_vector_type(8))) short short8;  // 8 bf16 (4 VGPRs)
typedef __attribute__((ext_vector_type(4))) float f32x4;
typedef __attribute__((ext_vector_type(4))) short short4v;

__device__ __forceinline__ s16 f2bf(float f) {
  union { float f; uint32_t u; } v; v.f = f;
  uint32_t u = v.u;
  uint32_t r = (u + 0x7fffu + ((u >> 16) & 1u)) >> 16;  // RNE
  return (s16)(uint16_t)r;
}
__device__ __forceinline__ float bf2f(s16 b) {
  union { uint32_t u; float f; } v; v.u = ((uint32_t)(uint16_t)b) << 16;
  return v.f;
}

#define GLOBAL_AS __attribute__((address_space(1)))
#define LDS_AS    __attribute__((address_space(3)))
__device__ __forceinline__ void gload_lds16(const void* g, void* l) {
  __builtin_amdgcn_global_load_lds((const GLOBAL_AS uint32_t*)g, (LDS_AS uint32_t*)l, 16, 0, 0);
}

// ---------------- GEMM: C(MxN) = A(MxK,row) @ B, B given as BT(NxK,row) -------
// Proven single-buffer 2-barrier K-loop, BK=64, XOR-swizzled LDS via
// pre-swizzled global source (linear LDS dest; same involution on read).
// SX: blockIdx.x indexes M(A) if true else N(BT); pick so blockIdx.x walks the
// LARGE operand (XCD = id%8 L2 locality).
// All outputs bf16:
//   gridDim.z>1 : obf_n + z*M*N gets raw bf16 partials (rowscale/addend null).
//   gridDim.z==1: v = acc*rowscale[row] + bf2f(addend_bf[idx]);
//                 obf_n[idx]=bf16(v); obf_t[col*M+row]=bf16(v).
template<int BM_, int BN_, bool SX>
__global__ void __launch_bounds__(256, 2)
gemm_t(const s16* __restrict__ A, const s16* __restrict__ BT,
       int M, int N, int K, int Kc,
       const float* __restrict__ rowscale,
       const s16* __restrict__ addend_bf,
       s16* __restrict__ obf_n, s16* __restrict__ obf_t)
{
  constexpr int SWA = BM_ / 32;       // staging sweeps (32 rows x 64k each)
  constexpr int SWB = BN_ / 32;
  constexpr int WM  = BM_ / 2;        // per-wave tile (2x2 wave grid)
  constexpr int WN  = BN_ / 2;
  constexpr int IM  = WM / 16;
  constexpr int JN  = WN / 16;

  __shared__ alignas(16) s16 lta[BM_ * 64];
  __shared__ alignas(16) s16 ltb[BN_ * 64];
  const int tid  = threadIdx.x;
  const int lane = tid & 63;
  const int wave = tid >> 6;
  const int wr = wave >> 1, wc = wave & 1;
  const int bm0 = (SX ? blockIdx.x : blockIdx.y) * BM_;
  const int bn0 = (SX ? blockIdx.y : blockIdx.x) * BN_;
  const int k0  = blockIdx.z * Kc;

  f32x4 acc[IM][JN];
  #pragma unroll
  for (int i = 0; i < IM; ++i)
    #pragma unroll
    for (int j = 0; j < JN; ++j)
      #pragma unroll
      for (int r = 0; r < 4; ++r) acc[i][j][r] = 0.0f;

  const int lrow = lane >> 3;
  const int lke  = ((lane & 7) ^ lrow) * 8;
  const s16* Ab = A  + (size_t)(bm0 + wave * 8 + lrow) * K + k0 + lke;
  const s16* Bb = BT + (size_t)(bn0 + wave * 8 + lrow) * K + k0 + lke;

  const int fr = lane & 15;
  const int k8 = (lane >> 4) * 8;
  const int sw = (fr & 7) * 8;       // read-side XOR: row&7 == fr&7

  const int nt = Kc / 64;
  for (int t = 0; t < nt; ++t) {
    const int ko = t * 64;
    #pragma unroll
    for (int s = 0; s < SWA; ++s)
      gload_lds16(Ab + (size_t)s * 32 * K + ko, &lta[s * 2048 + wave * 512]);
    #pragma unroll
    for (int s = 0; s < SWB; ++s)
      gload_lds16(Bb + (size_t)s * 32 * K + ko, &ltb[s * 2048 + wave * 512]);
    __syncthreads();   // drains vmcnt(0): tile fully staged

    short8 af[2][IM], bfv[2][JN];
    #pragma unroll
    for (int kk = 0; kk < 2; ++kk) {
      #pragma unroll
      for (int i = 0; i < IM; ++i)
        af[kk][i] = *(const short8*)&lta[(wr * WM + i * 16 + fr) * 64 + ((kk * 32 + k8) ^ sw)];
      #pragma unroll
      for (int j = 0; j < JN; ++j)
        bfv[kk][j] = *(const short8*)&ltb[(wc * WN + j * 16 + fr) * 64 + ((kk * 32 + k8) ^ sw)];
    }
    #pragma unroll
    for (int kk = 0; kk < 2; ++kk)
      #pragma unroll
      for (int i = 0; i < IM; ++i)
        #pragma unroll
        for (int j = 0; j < JN; ++j)
          acc[i][j] = __builtin_amdgcn_mfma_f32_16x16x32_bf16(af[kk][i], bfv[kk][j], acc[i][j], 0, 0, 0);
    __syncthreads();   // all waves done reading before next tile overwrites
  }

  // epilogue — C/D layout: col = lane&15, row = (lane>>4)*4 + reg
  s16* on = obf_n ? obf_n + (size_t)blockIdx.z * M * N : nullptr;
  const int r0 = (lane >> 4) * 4;
  const int cl = lane & 15;
  #pragma unroll
  for (int i = 0; i < IM; ++i) {
    const int gm = bm0 + wr * WM + i * 16 + r0;
    #pragma unroll
    for (int j = 0; j < JN; ++j) {
      const int gn = bn0 + wc * WN + j * 16 + cl;
      #pragma unroll
      for (int r = 0; r < 4; ++r) {
        const size_t idx = (size_t)(gm + r) * N + gn;
        float v = acc[i][j][r];
        if (rowscale)  v *= rowscale[gm + r];
        if (addend_bf) v += bf2f(addend_bf[idx]);
        if (on)    on[idx] = f2bf(v);
        if (obf_t) obf_t[(size_t)gn * M + (gm + r)] = f2bf(v);
      }
    }
  }
}

// ------- combine (KS=4, bf16 slices): fp32 and/or bf16 out -------------------
__global__ void __launch_bounds__(256)
k_combine4b(const s16* __restrict__ parts, size_t MN,
            float* __restrict__ Cf, s16* __restrict__ obf)
{
  const size_t i8 = ((size_t)blockIdx.x * 256 + threadIdx.x) * 8;
  if (i8 >= MN) return;
  short8 a = *(const short8*)(parts + i8);
  short8 b = *(const short8*)(parts + MN + i8);
  short8 c = *(const short8*)(parts + 2 * MN + i8);
  short8 d = *(const short8*)(parts + 3 * MN + i8);
  float v[8];
  #pragma unroll
  for (int r = 0; r < 8; ++r)
    v[r] = (bf2f(a[r]) + bf2f(b[r])) + (bf2f(c[r]) + bf2f(d[r]));
  if (Cf) {
    f32x4 lo, hi;
    #pragma unroll
    for (int r = 0; r < 4; ++r) { lo[r] = v[r]; hi[r] = v[r + 4]; }
    *(f32x4*)(Cf + i8) = lo;
    *(f32x4*)(Cf + i8 + 4) = hi;
  }
  if (obf) {
    short8 o;
    #pragma unroll
    for (int r = 0; r < 8; ++r) o[r] = f2bf(v[r]);
    *(short8*)(obf + i8) = o;
  }
}

// ------- fused combine + per-row Frobenius partial for FtF -------------------
__global__ void __launch_bounds__(256)
k_comb_frob(const s16* __restrict__ parts, int m,
            float* __restrict__ FtF, float* __restrict__ partial)
{
  const int row = blockIdx.x;
  const size_t MM = (size_t)m * m;
  float ss = 0.f;
  for (int c = threadIdx.x; c < m; c += 256) {
    const size_t idx = (size_t)row * m + c;
    float v = (bf2f(parts[idx]) + bf2f(parts[MM + idx]))
            + (bf2f(parts[2 * MM + idx]) + bf2f(parts[3 * MM + idx]));
    FtF[idx] = v;
    ss += v * v;
  }
  __shared__ float red[256];
  red[threadIdx.x] = ss; __syncthreads();
  for (int o = 128; o > 0; o >>= 1) {
    if (threadIdx.x < o) red[threadIdx.x] += red[threadIdx.x + o];
    __syncthreads();
  }
  if (threadIdx.x == 0) partial[row] = red[0];
}

// ------- fused norm-finalize + g0 scale --------------------------------------
// Every block computes the SAME fixed-order reduction of partial[0..m) (bitwise
// identical rnorm), then scales its own row of FtF into g0.
__global__ void __launch_bounds__(256)
k_normscale(const float* __restrict__ partial, const float* __restrict__ FtF,
            s16* __restrict__ g0, int m)
{
  float s = 0.f;
  for (int i = threadIdx.x; i < m; i += 256) s += partial[i];
  __shared__ float red[256];
  red[threadIdx.x] = s; __syncthreads();
  for (int o = 128; o > 0; o >>= 1) {
    if (threadIdx.x < o) red[threadIdx.x] += red[threadIdx.x + o];
    __syncthreads();
  }
  const float rn = 1.0f / (sqrtf(red[0]) + 1e-12f);
  const int row = blockIdx.x;
  for (int c = threadIdx.x; c < m; c += 256) {
    const size_t idx = (size_t)row * m + c;
    g0[idx] = f2bf(FtF[idx] * rn);
  }
}

// ------- one fused conversion kernel: Q dual, X plain, F^T, colscale ---------
__device__ __forceinline__ void cvt64(const float* __restrict__ in,
                                      s16* __restrict__ outp, s16* __restrict__ outt,
                                      int R, int C, int bx64, int by64,
                                      float (*t)[65], int tid)
{
  const int bx = bx64 * 64, by = by64 * 64;
  const int r0 = tid >> 4;         // 0..15
  const int c4 = (tid & 15) * 4;   // 0..60
  #pragma unroll
  for (int rr = 0; rr < 4; ++rr) {
    const int r = rr * 16 + r0;
    const f32x4 v = *(const f32x4*)(in + (size_t)(by + r) * C + bx + c4);
    if (outp) {
      short4v o;
      #pragma unroll
      for (int j = 0; j < 4; ++j) o[j] = f2bf(v[j]);
      *(short4v*)(outp + (size_t)(by + r) * C + bx + c4) = o;
    }
    if (outt) {
      t[r][c4] = v[0]; t[r][c4 + 1] = v[1]; t[r][c4 + 2] = v[2]; t[r][c4 + 3] = v[3];
    }
  }
  if (outt) {
    __syncthreads();
    const int cc = tid >> 4;
    const int r4 = (tid & 15) * 4;
    #pragma unroll
    for (int p = 0; p < 4; ++p) {
      const int c = p * 16 + cc;
      short4v o;
      #pragma unroll
      for (int j = 0; j < 4; ++j) o[j] = f2bf(t[r4 + j][c]);
      *(short4v*)(outt + (size_t)(bx + c) * R + by + r4) = o;
    }
  }
}

__global__ void __launch_bounds__(256)
k_cvt_all(const float* __restrict__ Q, const float* __restrict__ X,
          const float* __restrict__ F, const float* __restrict__ lam,
          s16* __restrict__ Qbf, s16* __restrict__ QTbf,
          s16* __restrict__ Xbf, s16* __restrict__ FTbf,
          float* __restrict__ scal, int m, int n)
{
  __shared__ float t[64][65];
  const int tid = threadIdx.x;
  int b = blockIdx.x;
  const int qx = n / 64;
  const int nQ = qx * qx;
  const int nX = qx * (m / 64);
  const int nF = (m / 64) * (m / 64);
  if (b < nQ) {
    cvt64(Q, Qbf, QTbf, n, n, b % qx, b / qx, t, tid);
  } else if ((b -= nQ) < nX) {
    cvt64(X, Xbf, nullptr, m, n, b % qx, b / qx, t, tid);
  } else if ((b -= nX) < nF) {
    cvt64(F, nullptr, FTbf, m, m, b % (m / 64), b / (m / 64), t, tid);
  } else {
    for (int j = tid; j < n; j += 256) {
      float v = 0.8f * lam[j];
      scal[j] = v;
      scal[n + j] = v * v;
    }
  }
}

// ---------------- driver ----------------
extern "C" void kernel_launch(void* const* d_in, const int* in_sizes, int n_in,
                              void* d_out, int out_size, void* d_ws, size_t ws_size,
                              hipStream_t stream)
{
  const float* X   = (const float*)d_in[0];   // (m, n)
  const float* F   = (const float*)d_in[1];   // (m, m)
  const float* Q   = (const float*)d_in[2];   // (n, n)
  const float* lam = (const float*)d_in[3];   // (n,)

  int m = 1;
  while ((long long)m * m < (long long)in_sizes[1]) ++m;   // 512
  const int n = in_sizes[0] / m;                           // 4096
  const size_t MN = (size_t)m * n;                         // 2M elements
  const size_t MM = (size_t)m * m;

  char* w = (char*)d_ws;
  auto take = [&](size_t bytes) -> void* {
    char* p = w;
    w += (bytes + 255) & ~(size_t)255;
    return (void*)p;
  };

  // ~95 MB total; ws ~256 MB (fill evidence). No overlays except Splain=Sb0.
  s16*   Qbf  = (s16*)take((size_t)n * n * 2);   // Q        (bf16)
  s16*   QTbf = (s16*)take((size_t)n * n * 2);   // Q^T      (bf16)
  s16*   Xbf  = (s16*)take(MN * 2);              // X        (bf16 plain)
  s16*   FTbf = (s16*)take(MM * 2);              // F^T
  s16*   g[2];
  for (int k = 0; k < 2; ++k) g[k] = (s16*)take(MM * 2);   // gF, gF^2
  float* FtF  = (float*)take(MM * 4);
  float* scal = (float*)take((size_t)2 * n * 4);
  float* part = (float*)take((size_t)m * 4);
  s16*   Sb0  = (s16*)take(MN * 2);              // St bf16 ping
  s16*   Sb1  = (s16*)take(MN * 2);              // St bf16 pong
  s16*   partsb = (s16*)take(4 * MN * 2);        // KS=4 bf16 partial slices
  (void)ws_size; (void)n_in; (void)out_size;

  s16* Splain = Sb0;   // Sb0 dead after doubling k=0 consumed it

  const int KS = 4;
  const dim3 blk(256);
  const int nCvt = (n / 64) * (n / 64) + (n / 64) * (m / 64)
                 + (m / 64) * (m / 64) + 1;

  // 1) one fused conversion kernel (Q dual, X, F^T, colscale)
  k_cvt_all<<<dim3(nCvt), blk, 0, stream>>>(Q, X, F, lam, Qbf, QTbf, Xbf, FTbf,
                                            scal, m, n);

  // 2) FtF = F^T F (A = F^T, BT = F^T => B = F), KS=4 bf16 partials
  gemm_t<64, 64, false><<<dim3(m / 64, m / 64, KS), blk, 0, stream>>>(
      FTbf, FTbf, m, m, m, m / KS, nullptr, nullptr, partsb, nullptr);
  // 3) fused combine + Frobenius partial; fused norm + g0 scale
  k_comb_frob<<<dim3(m), blk, 0, stream>>>(partsb, m, FtF, part);
  k_normscale<<<dim3(m), blk, 0, stream>>>(part, FtF, g[0], m);

  // 4) one squaring: g1 = bf16(g0 @ g0) (symmetric), KS=4 bf16 partials
  gemm_t<64, 64, false><<<dim3(m / 64, m / 64, KS), blk, 0, stream>>>(
      g[0], g[0], m, m, m, m / KS, nullptr, nullptr, partsb, nullptr);
  k_combine4b<<<dim3((unsigned)(MM / 2048)), blk, 0, stream>>>(partsb, MM, nullptr, g[1]);

  // 5) St0 = Q^T X^T  (A = Q^T [big -> blockIdx.x], BT = X), 128x64 KS=4
  //    -> grid (32,8,4) = 1024 blocks, ~4-6 resident blocks/CU
  gemm_t<128, 64, true><<<dim3(n / 128, m / 64, KS), blk, 0, stream>>>(
      QTbf, Xbf, n, m, n, n / KS, nullptr, nullptr, partsb, nullptr);
  k_combine4b<<<dim3((unsigned)(MN / 2048)), blk, 0, stream>>>(partsb, MN, nullptr, Sb0);

  // 6) 2 doublings (4 Neumann terms): St_{k+1} = St_k + rs_k.(St_k @ g_k)
  gemm_t<64, 64, true><<<dim3(n / 64, m / 64, 1), blk, 0, stream>>>(
      Sb0, g[0], n, m, m, m, scal + 0 * (size_t)n, Sb0, Sb1, nullptr);
  // last: emit only S plain (m x n) via transposed bf16 write
  gemm_t<64, 64, true><<<dim3(n / 64, m / 64, 1), blk, 0, stream>>>(
      Sb1, g[1], n, m, m, m, scal + 1 * (size_t)n, Sb1, nullptr, Splain);

  // 7) Z = S @ Q^T  (A = S plain, BT = Q [big -> blockIdx.x]), 64x128 KS=4
  gemm_t<64, 128, false><<<dim3(n / 128, m / 64, KS), blk, 0, stream>>>(
      Splain, Qbf, m, n, n, n / KS, nullptr, nullptr, partsb, nullptr);
  k_combine4b<<<dim3((unsigned)(MN / 2048)), blk, 0, stream>>>(partsb, MN, (float*)d_out, nullptr);
}

// Round 9
// 134.205 us; speedup vs baseline: 3.7549x; 1.0070x over previous
//
#include <hip/hip_runtime.h>
#include <stdint.h>

typedef short s16;
typedef __attribute__((ext_vector_type(8))) short short8;  // 8 bf16 (4 VGPRs)
typedef __attribute__((ext_vector_type(4))) float f32x4;
typedef __attribute__((ext_vector_type(4))) short short4v;
typedef __attribute__((ext_vector_type(4))) unsigned int u32x4;

__device__ __forceinline__ s16 f2bf(float f) {
  union { float f; uint32_t u; } v; v.f = f;
  uint32_t u = v.u;
  uint32_t r = (u + 0x7fffu + ((u >> 16) & 1u)) >> 16;  // RNE
  return (s16)(uint16_t)r;
}
__device__ __forceinline__ float bf2f(s16 b) {
  union { uint32_t u; float f; } v; v.u = ((uint32_t)(uint16_t)b) << 16;
  return v.f;
}

#define GLOBAL_AS __attribute__((address_space(1)))
#define LDS_AS    __attribute__((address_space(3)))
__device__ __forceinline__ void gload_lds16(const void* g, void* l) {
  __builtin_amdgcn_global_load_lds((const GLOBAL_AS uint32_t*)g, (LDS_AS uint32_t*)l, 16, 0, 0);
}

// ---------------- GEMM: C(MxN) = A(MxK,row) @ B, B given as BT(NxK,row) -------
// Proven single-buffer 2-barrier K-loop, BK=64, XOR-swizzled LDS via
// pre-swizzled global source (linear LDS dest; same involution on read).
// SX: blockIdx.x-dir indexes M(A) if true else N(BT) — big operand on x.
// MAP=0: plain 3D grid. MAP=1: 1D grid of gx*gy*4 blocks, XCD-aware decode:
//   fid%8 -> (K-slice z = c&3, big-dim half = c>>2); each XCD then works ONE
//   K-slice and a contiguous half of the big operand's panels, shrinking its
//   L2 working set (~5 MB vs 8 MB at plain round-robin). Bijective.
// All outputs bf16:
//   KS>1 : obf_n + z*M*N gets raw bf16 partials (rowscale/addend null).
//   KS==1: v = acc*rowscale[row] + bf2f(addend_bf[idx]);
//          obf_n[idx]=bf16(v); obf_t[col*M+row]=bf16(v).
template<int BM_, int BN_, bool SX, int MAP>
__global__ void __launch_bounds__(256, 2)
gemm_t(const s16* __restrict__ A, const s16* __restrict__ BT,
       int M, int N, int K, int Kc, int gx,
       const float* __restrict__ rowscale,
       const s16* __restrict__ addend_bf,
       s16* __restrict__ obf_n, s16* __restrict__ obf_t)
{
  constexpr int SWA = BM_ / 32;       // staging sweeps (32 rows x 64k each)
  constexpr int SWB = BN_ / 32;
  constexpr int WM  = BM_ / 2;        // per-wave tile (2x2 wave grid)
  constexpr int WN  = BN_ / 2;
  constexpr int IM  = WM / 16;
  constexpr int JN  = WN / 16;

  __shared__ alignas(16) s16 lta[BM_ * 64];
  __shared__ alignas(16) s16 ltb[BN_ * 64];
  const int tid  = threadIdx.x;
  const int lane = tid & 63;
  const int wave = tid >> 6;
  const int wr = wave >> 1, wc = wave & 1;

  int bxi, byi, bzi;
  if (MAP == 1) {
    const int fid = blockIdx.x;
    const int c  = fid & 7;
    const int tt = fid >> 3;
    const int gxh = gx >> 1;
    bzi = c & 3;
    bxi = (c >> 2) * gxh + tt % gxh;
    byi = tt / gxh;
  } else {
    bxi = blockIdx.x; byi = blockIdx.y; bzi = blockIdx.z;
  }
  const int bm0 = (SX ? bxi : byi) * BM_;
  const int bn0 = (SX ? byi : bxi) * BN_;
  const int k0  = bzi * Kc;

  f32x4 acc[IM][JN];
  #pragma unroll
  for (int i = 0; i < IM; ++i)
    #pragma unroll
    for (int j = 0; j < JN; ++j)
      #pragma unroll
      for (int r = 0; r < 4; ++r) acc[i][j][r] = 0.0f;

  const int lrow = lane >> 3;
  const int lke  = ((lane & 7) ^ lrow) * 8;
  const s16* Ab = A  + (size_t)(bm0 + wave * 8 + lrow) * K + k0 + lke;
  const s16* Bb = BT + (size_t)(bn0 + wave * 8 + lrow) * K + k0 + lke;

  const int fr = lane & 15;
  const int k8 = (lane >> 4) * 8;
  const int sw = (fr & 7) * 8;       // read-side XOR: row&7 == fr&7

  const int nt = Kc / 64;
  for (int t = 0; t < nt; ++t) {
    const int ko = t * 64;
    #pragma unroll
    for (int s = 0; s < SWA; ++s)
      gload_lds16(Ab + (size_t)s * 32 * K + ko, &lta[s * 2048 + wave * 512]);
    #pragma unroll
    for (int s = 0; s < SWB; ++s)
      gload_lds16(Bb + (size_t)s * 32 * K + ko, &ltb[s * 2048 + wave * 512]);
    __syncthreads();   // drains vmcnt(0): tile fully staged

    short8 af[2][IM], bfv[2][JN];
    #pragma unroll
    for (int kk = 0; kk < 2; ++kk) {
      #pragma unroll
      for (int i = 0; i < IM; ++i)
        af[kk][i] = *(const short8*)&lta[(wr * WM + i * 16 + fr) * 64 + ((kk * 32 + k8) ^ sw)];
      #pragma unroll
      for (int j = 0; j < JN; ++j)
        bfv[kk][j] = *(const short8*)&ltb[(wc * WN + j * 16 + fr) * 64 + ((kk * 32 + k8) ^ sw)];
    }
    #pragma unroll
    for (int kk = 0; kk < 2; ++kk)
      #pragma unroll
      for (int i = 0; i < IM; ++i)
        #pragma unroll
        for (int j = 0; j < JN; ++j)
          acc[i][j] = __builtin_amdgcn_mfma_f32_16x16x32_bf16(af[kk][i], bfv[kk][j], acc[i][j], 0, 0, 0);
    __syncthreads();   // all waves done reading before next tile overwrites
  }

  // epilogue — C/D layout: col = lane&15, row = (lane>>4)*4 + reg
  s16* on = obf_n ? obf_n + (size_t)bzi * M * N : nullptr;
  const int r0 = (lane >> 4) * 4;
  const int cl = lane & 15;
  #pragma unroll
  for (int i = 0; i < IM; ++i) {
    const int gm = bm0 + wr * WM + i * 16 + r0;
    #pragma unroll
    for (int j = 0; j < JN; ++j) {
      const int gn = bn0 + wc * WN + j * 16 + cl;
      #pragma unroll
      for (int r = 0; r < 4; ++r) {
        const size_t idx = (size_t)(gm + r) * N + gn;
        float v = acc[i][j][r];
        if (rowscale)  v *= rowscale[gm + r];
        if (addend_bf) v += bf2f(addend_bf[idx]);
        if (on)    on[idx] = f2bf(v);
        if (obf_t) obf_t[(size_t)gn * M + (gm + r)] = f2bf(v);
      }
    }
  }
}

// ------- combine (KS=4, bf16 slices): fp32 and/or bf16 out -------------------
__global__ void __launch_bounds__(256)
k_combine4b(const s16* __restrict__ parts, size_t MN,
            float* __restrict__ Cf, s16* __restrict__ obf)
{
  const size_t i8 = ((size_t)blockIdx.x * 256 + threadIdx.x) * 8;
  if (i8 >= MN) return;
  short8 a = *(const short8*)(parts + i8);
  short8 b = *(const short8*)(parts + MN + i8);
  short8 c = *(const short8*)(parts + 2 * MN + i8);
  short8 d = *(const short8*)(parts + 3 * MN + i8);
  float v[8];
  #pragma unroll
  for (int r = 0; r < 8; ++r)
    v[r] = (bf2f(a[r]) + bf2f(b[r])) + (bf2f(c[r]) + bf2f(d[r]));
  if (Cf) {
    f32x4 lo, hi;
    #pragma unroll
    for (int r = 0; r < 4; ++r) { lo[r] = v[r]; hi[r] = v[r + 4]; }
    *(f32x4*)(Cf + i8) = lo;
    *(f32x4*)(Cf + i8 + 4) = hi;
  }
  if (obf) {
    short8 o;
    #pragma unroll
    for (int r = 0; r < 8; ++r) o[r] = f2bf(v[r]);
    *(short8*)(obf + i8) = o;
  }
}

// ------- fused combine + per-row Frobenius partial for FtF -------------------
__global__ void __launch_bounds__(256)
k_comb_frob(const s16* __restrict__ parts, int m,
            float* __restrict__ FtF, float* __restrict__ partial)
{
  const int row = blockIdx.x;
  const size_t MM = (size_t)m * m;
  float ss = 0.f;
  for (int c = threadIdx.x; c < m; c += 256) {
    const size_t idx = (size_t)row * m + c;
    float v = (bf2f(parts[idx]) + bf2f(parts[MM + idx]))
            + (bf2f(parts[2 * MM + idx]) + bf2f(parts[3 * MM + idx]));
    FtF[idx] = v;
    ss += v * v;
  }
  __shared__ float red[256];
  red[threadIdx.x] = ss; __syncthreads();
  for (int o = 128; o > 0; o >>= 1) {
    if (threadIdx.x < o) red[threadIdx.x] += red[threadIdx.x + o];
    __syncthreads();
  }
  if (threadIdx.x == 0) partial[row] = red[0];
}

// ------- fused norm-finalize + g0 scale (bitwise-identical rn per block) -----
__global__ void __launch_bounds__(256)
k_normscale(const float* __restrict__ partial, const float* __restrict__ FtF,
            s16* __restrict__ g0, int m)
{
  float s = 0.f;
  for (int i = threadIdx.x; i < m; i += 256) s += partial[i];
  __shared__ float red[256];
  red[threadIdx.x] = s; __syncthreads();
  for (int o = 128; o > 0; o >>= 1) {
    if (threadIdx.x < o) red[threadIdx.x] += red[threadIdx.x + o];
    __syncthreads();
  }
  const float rn = 1.0f / (sqrtf(red[0]) + 1e-12f);
  const int row = blockIdx.x;
  for (int c = threadIdx.x; c < m; c += 256) {
    const size_t idx = (size_t)row * m + c;
    g0[idx] = f2bf(FtF[idx] * rn);
  }
}

// ------- fused conversion: 128x128 tiles, 256B-run stores --------------------
// Plain: straight reg path, f32x4 x2 -> short8 (16B/lane; rows 128 bf16 = 256B).
// Transposed: bf16-pair-packed u32 LDS [128][65] (33 KB); phase-2 reads 8 u32s
// per lane (8-way bank alias — LDS pipe is ~3us total, not the bottleneck),
// unpacks column c, writes short8 -> 16 lanes x 16B = 256B runs.
__device__ __forceinline__ void cvt128(const float* __restrict__ in,
                                       s16* __restrict__ outp, s16* __restrict__ outt,
                                       int R, int C, int bx128, int by128,
                                       uint32_t (*t32)[65], int tid)
{
  const int bx = bx128 * 128, by = by128 * 128;
  const int u = tid & 15, v = tid >> 4;     // v in 0..15
  const int c8 = u * 8;
  #pragma unroll
  for (int rr = 0; rr < 8; ++rr) {
    const int r = rr * 16 + v;
    const float* src = in + (size_t)(by + r) * C + bx + c8;
    const f32x4 a = *(const f32x4*)src;
    const f32x4 b = *(const f32x4*)(src + 4);
    s16 e[8];
    e[0] = f2bf(a[0]); e[1] = f2bf(a[1]); e[2] = f2bf(a[2]); e[3] = f2bf(a[3]);
    e[4] = f2bf(b[0]); e[5] = f2bf(b[1]); e[6] = f2bf(b[2]); e[7] = f2bf(b[3]);
    if (outp) {
      short8 o;
      #pragma unroll
      for (int j = 0; j < 8; ++j) o[j] = e[j];
      *(short8*)(outp + (size_t)(by + r) * C + bx + c8) = o;
    }
    if (outt) {
      u32x4 w;
      #pragma unroll
      for (int j = 0; j < 4; ++j)
        w[j] = ((uint32_t)(uint16_t)e[2 * j]) | (((uint32_t)(uint16_t)e[2 * j + 1]) << 16);
      *(u32x4*)&t32[r][c8 >> 1] = w;
    }
  }
  if (outt) {
    __syncthreads();
    const int r8 = u * 8;
    #pragma unroll
    for (int p = 0; p < 8; ++p) {
      const int c  = p * 16 + v;
      const int cw = c >> 1;
      const int sh = (c & 1) * 16;
      short8 o;
      #pragma unroll
      for (int j = 0; j < 8; ++j)
        o[j] = (s16)(uint16_t)((t32[r8 + j][cw] >> sh) & 0xffffu);
      *(short8*)(outt + (size_t)(bx + c) * R + by + r8) = o;
    }
  }
}

__global__ void __launch_bounds__(256)
k_cvt_all(const float* __restrict__ Q, const float* __restrict__ X,
          const float* __restrict__ F, const float* __restrict__ lam,
          s16* __restrict__ Qbf, s16* __restrict__ QTbf,
          s16* __restrict__ Xbf, s16* __restrict__ FTbf,
          float* __restrict__ scal, int m, int n)
{
  __shared__ uint32_t t32[128][65];
  const int tid = threadIdx.x;
  int b = blockIdx.x;
  const int qx = n / 128;
  const int mx = m / 128;
  const int nQ = qx * qx;
  const int nX = qx * mx;
  const int nF = mx * mx;
  if (b < nQ) {
    cvt128(Q, Qbf, QTbf, n, n, b % qx, b / qx, t32, tid);
  } else if ((b -= nQ) < nX) {
    cvt128(X, Xbf, nullptr, m, n, b % qx, b / qx, t32, tid);
  } else if ((b -= nX) < nF) {
    cvt128(F, nullptr, FTbf, m, m, b % mx, b / mx, t32, tid);
  } else {
    for (int j = tid; j < n; j += 256) {
      float v = 0.8f * lam[j];
      scal[j] = v;
      scal[n + j] = v * v;
    }
  }
}

// ---------------- driver ----------------
extern "C" void kernel_launch(void* const* d_in, const int* in_sizes, int n_in,
                              void* d_out, int out_size, void* d_ws, size_t ws_size,
                              hipStream_t stream)
{
  const float* X   = (const float*)d_in[0];   // (m, n)
  const float* F   = (const float*)d_in[1];   // (m, m)
  const float* Q   = (const float*)d_in[2];   // (n, n)
  const float* lam = (const float*)d_in[3];   // (n,)

  int m = 1;
  while ((long long)m * m < (long long)in_sizes[1]) ++m;   // 512
  const int n = in_sizes[0] / m;                           // 4096
  const size_t MN = (size_t)m * n;                         // 2M elements
  const size_t MM = (size_t)m * m;

  char* w = (char*)d_ws;
  auto take = [&](size_t bytes) -> void* {
    char* p = w;
    w += (bytes + 255) & ~(size_t)255;
    return (void*)p;
  };

  // ~95 MB total; ws ~256 MB (fill evidence). No overlays except Splain=Sb0.
  s16*   Qbf  = (s16*)take((size_t)n * n * 2);   // Q        (bf16)
  s16*   QTbf = (s16*)take((size_t)n * n * 2);   // Q^T      (bf16)
  s16*   Xbf  = (s16*)take(MN * 2);              // X        (bf16 plain)
  s16*   FTbf = (s16*)take(MM * 2);              // F^T
  s16*   g[2];
  for (int k = 0; k < 2; ++k) g[k] = (s16*)take(MM * 2);   // gF, gF^2
  float* FtF  = (float*)take(MM * 4);
  float* scal = (float*)take((size_t)2 * n * 4);
  float* part = (float*)take((size_t)m * 4);
  s16*   Sb0  = (s16*)take(MN * 2);              // St bf16 ping
  s16*   Sb1  = (s16*)take(MN * 2);              // St bf16 pong
  s16*   partsb = (s16*)take(4 * MN * 2);        // KS=4 bf16 partial slices
  (void)ws_size; (void)n_in; (void)out_size;

  s16* Splain = Sb0;   // Sb0 dead after doubling k=0 consumed it

  const int KS = 4;
  const dim3 blk(256);
  const int nCvt = (n / 128) * (n / 128) + (n / 128) * (m / 128)
                 + (m / 128) * (m / 128) + 1;

  // 1) one fused conversion kernel (Q dual, X, F^T, colscale), 256B-run stores
  k_cvt_all<<<dim3(nCvt), blk, 0, stream>>>(Q, X, F, lam, Qbf, QTbf, Xbf, FTbf,
                                            scal, m, n);

  // 2) FtF = F^T F (A = F^T, BT = F^T => B = F), KS=4 bf16 partials
  gemm_t<64, 64, false, 0><<<dim3(m / 64, m / 64, KS), blk, 0, stream>>>(
      FTbf, FTbf, m, m, m, m / KS, 0, nullptr, nullptr, partsb, nullptr);
  // 3) fused combine + Frobenius partial; fused norm + g0 scale
  k_comb_frob<<<dim3(m), blk, 0, stream>>>(partsb, m, FtF, part);
  k_normscale<<<dim3(m), blk, 0, stream>>>(part, FtF, g[0], m);

  // 4) one squaring: g1 = bf16(g0 @ g0) (symmetric), KS=4 bf16 partials
  gemm_t<64, 64, false, 0><<<dim3(m / 64, m / 64, KS), blk, 0, stream>>>(
      g[0], g[0], m, m, m, m / KS, 0, nullptr, nullptr, partsb, nullptr);
  k_combine4b<<<dim3((unsigned)(MM / 2048)), blk, 0, stream>>>(partsb, MM, nullptr, g[1]);

  // 5) St0 = Q^T X^T  (A = Q^T [big -> x], BT = X), 128x64 KS=4, XCD MAP=1
  gemm_t<128, 64, true, 1><<<dim3((n / 128) * (m / 64) * KS), blk, 0, stream>>>(
      QTbf, Xbf, n, m, n, n / KS, n / 128, nullptr, nullptr, partsb, nullptr);
  k_combine4b<<<dim3((unsigned)(MN / 2048)), blk, 0, stream>>>(partsb, MN, nullptr, Sb0);

  // 6) 2 doublings (4 Neumann terms): St_{k+1} = St_k + rs_k.(St_k @ g_k)
  gemm_t<64, 64, true, 0><<<dim3(n / 64, m / 64, 1), blk, 0, stream>>>(
      Sb0, g[0], n, m, m, m, 0, scal + 0 * (size_t)n, Sb0, Sb1, nullptr);
  // last: emit only S plain (m x n) via transposed bf16 write
  gemm_t<64, 64, true, 0><<<dim3(n / 64, m / 64, 1), blk, 0, stream>>>(
      Sb1, g[1], n, m, m, m, 0, scal + 1 * (size_t)n, Sb1, nullptr, Splain);

  // 7) Z = S @ Q^T  (A = S plain, BT = Q [big -> x]), 64x128 KS=4, XCD MAP=1
  gemm_t<64, 128, false, 1><<<dim3((n / 128) * (m / 64) * KS), blk, 0, stream>>>(
      Splain, Qbf, m, n, n, n / KS, n / 128, nullptr, nullptr, partsb, nullptr);
  k_combine4b<<<dim3((unsigned)(MN / 2048)), blk, 0, stream>>>(partsb, MN, (float*)d_out, nullptr);
}

// Round 10
// 133.026 us; speedup vs baseline: 3.7882x; 1.0089x over previous
//
#include <hip/hip_runtime.h>
#include <stdint.h>

typedef short s16;
typedef __attribute__((ext_vector_type(8))) short short8;  // 8 bf16 (4 VGPRs)
typedef __attribute__((ext_vector_type(4))) float f32x4;
typedef __attribute__((ext_vector_type(4))) unsigned int u32x4;

__device__ __forceinline__ s16 f2bf(float f) {
  union { float f; uint32_t u; } v; v.f = f;
  uint32_t u = v.u;
  uint32_t r = (u + 0x7fffu + ((u >> 16) & 1u)) >> 16;  // RNE
  return (s16)(uint16_t)r;
}
__device__ __forceinline__ float bf2f(s16 b) {
  union { uint32_t u; float f; } v; v.u = ((uint32_t)(uint16_t)b) << 16;
  return v.f;
}

#define GLOBAL_AS __attribute__((address_space(1)))
#define LDS_AS    __attribute__((address_space(3)))
__device__ __forceinline__ void gload_lds16(const void* g, void* l) {
  __builtin_amdgcn_global_load_lds((const GLOBAL_AS uint32_t*)g, (LDS_AS uint32_t*)l, 16, 0, 0);
}

// ---------------- GEMM body: C(MxN) = A(MxK,row) @ B, B given as BT(NxK,row) --
// PROVEN single-buffer 2-barrier K-loop, BK=64, XOR-swizzled LDS via
// pre-swizzled global source. Verbatim from rounds 3-9; only hoisted into a
// __device__ function (LDS via pointers) so independent GEMMs can share one
// launch. All outputs bf16: obf_n gets raw partials at + bzi*M*N (when
// rowscale/addend null) or the fused v = acc*rowscale[row]+bf2f(addend[idx]);
// obf_t writes bf16 transposed [col*M+row].
template<int BM_, int BN_, bool SX>
__device__ __forceinline__ void
gemm_body(const s16* __restrict__ A, const s16* __restrict__ BT,
          int M, int N, int K, int Kc, int bxi, int byi, int bzi,
          const float* __restrict__ rowscale,
          const s16* __restrict__ addend_bf,   // read-only; may equal A
          s16* __restrict__ obf_n, s16* __restrict__ obf_t,
          s16* lta, s16* ltb)
{
  constexpr int SWA = BM_ / 32;
  constexpr int SWB = BN_ / 32;
  constexpr int WM  = BM_ / 2;
  constexpr int WN  = BN_ / 2;
  constexpr int IM  = WM / 16;
  constexpr int JN  = WN / 16;

  const int tid  = threadIdx.x;
  const int lane = tid & 63;
  const int wave = tid >> 6;
  const int wr = wave >> 1, wc = wave & 1;
  const int bm0 = (SX ? bxi : byi) * BM_;
  const int bn0 = (SX ? byi : bxi) * BN_;
  const int k0  = bzi * Kc;

  f32x4 acc[IM][JN];
  #pragma unroll
  for (int i = 0; i < IM; ++i)
    #pragma unroll
    for (int j = 0; j < JN; ++j)
      #pragma unroll
      for (int r = 0; r < 4; ++r) acc[i][j][r] = 0.0f;

  const int lrow = lane >> 3;
  const int lke  = ((lane & 7) ^ lrow) * 8;
  const s16* Ab = A  + (size_t)(bm0 + wave * 8 + lrow) * K + k0 + lke;
  const s16* Bb = BT + (size_t)(bn0 + wave * 8 + lrow) * K + k0 + lke;

  const int fr = lane & 15;
  const int k8 = (lane >> 4) * 8;
  const int sw = (fr & 7) * 8;       // read-side XOR: row&7 == fr&7

  const int nt = Kc / 64;
  for (int t = 0; t < nt; ++t) {
    const int ko = t * 64;
    #pragma unroll
    for (int s = 0; s < SWA; ++s)
      gload_lds16(Ab + (size_t)s * 32 * K + ko, &lta[s * 2048 + wave * 512]);
    #pragma unroll
    for (int s = 0; s < SWB; ++s)
      gload_lds16(Bb + (size_t)s * 32 * K + ko, &ltb[s * 2048 + wave * 512]);
    __syncthreads();   // drains vmcnt(0): tile fully staged

    short8 af[2][IM], bfv[2][JN];
    #pragma unroll
    for (int kk = 0; kk < 2; ++kk) {
      #pragma unroll
      for (int i = 0; i < IM; ++i)
        af[kk][i] = *(const short8*)&lta[(wr * WM + i * 16 + fr) * 64 + ((kk * 32 + k8) ^ sw)];
      #pragma unroll
      for (int j = 0; j < JN; ++j)
        bfv[kk][j] = *(const short8*)&ltb[(wc * WN + j * 16 + fr) * 64 + ((kk * 32 + k8) ^ sw)];
    }
    #pragma unroll
    for (int kk = 0; kk < 2; ++kk)
      #pragma unroll
      for (int i = 0; i < IM; ++i)
        #pragma unroll
        for (int j = 0; j < JN; ++j)
          acc[i][j] = __builtin_amdgcn_mfma_f32_16x16x32_bf16(af[kk][i], bfv[kk][j], acc[i][j], 0, 0, 0);
    __syncthreads();   // all waves done reading before next tile overwrites
  }

  // epilogue — C/D layout: col = lane&15, row = (lane>>4)*4 + reg
  s16* on = obf_n ? obf_n + (size_t)bzi * M * N : nullptr;
  const int r0 = (lane >> 4) * 4;
  const int cl = lane & 15;
  #pragma unroll
  for (int i = 0; i < IM; ++i) {
    const int gm = bm0 + wr * WM + i * 16 + r0;
    #pragma unroll
    for (int j = 0; j < JN; ++j) {
      const int gn = bn0 + wc * WN + j * 16 + cl;
      #pragma unroll
      for (int r = 0; r < 4; ++r) {
        const size_t idx = (size_t)(gm + r) * N + gn;
        float v = acc[i][j][r];
        if (rowscale)  v *= rowscale[gm + r];
        if (addend_bf) v += bf2f(addend_bf[idx]);
        if (on)    on[idx] = f2bf(v);
        if (obf_t) obf_t[(size_t)gn * M + (gm + r)] = f2bf(v);
      }
    }
  }
}

// ------- standalone GEMM wrapper (MAP=1: XCD-aware 1D decode) ----------------
template<int BM_, int BN_, bool SX, int MAP>
__global__ void __launch_bounds__(256, 2)
gemm_t(const s16* __restrict__ A, const s16* __restrict__ BT,
       int M, int N, int K, int Kc, int gx,
       const float* __restrict__ rowscale,
       const s16* __restrict__ addend_bf,
       s16* __restrict__ obf_n, s16* __restrict__ obf_t)
{
  __shared__ alignas(16) s16 lds[BM_ * 64 + BN_ * 64];
  int bxi, byi, bzi;
  if (MAP == 1) {
    const int fid = blockIdx.x;
    const int c  = fid & 7;
    const int tt = fid >> 3;
    const int gxh = gx >> 1;
    bzi = c & 3;
    bxi = (c >> 2) * gxh + tt % gxh;
    byi = tt / gxh;
  } else {
    bxi = blockIdx.x; byi = blockIdx.y; bzi = blockIdx.z;
  }
  gemm_body<BM_, BN_, SX>(A, BT, M, N, K, Kc, bxi, byi, bzi,
                          rowscale, addend_bf, obf_n, obf_t, lds, lds + BM_ * 64);
}

// ------- mega1: st5 GEMM (St0 partials) + FtF GEMM (partials) ----------------
__global__ void __launch_bounds__(256, 2)
k_mega1(const s16* __restrict__ QT, const s16* __restrict__ Xb,
        const s16* __restrict__ FT, int m, int n,
        s16* __restrict__ parts_mn, s16* __restrict__ parts_mm)
{
  __shared__ alignas(16) s16 lds[192 * 64];   // 24.5 KB (max of both paths)
  int b = blockIdx.x;
  const int gx = n / 128;
  const int nSt5 = gx * (m / 64) * 4;         // 1024
  if (b < nSt5) {
    const int c = b & 7, tt = b >> 3, gxh = gx >> 1;
    const int bzi = c & 3, bxi = (c >> 2) * gxh + tt % gxh, byi = tt / gxh;
    gemm_body<128, 64, true>(QT, Xb, n, m, n, n / 4, bxi, byi, bzi,
                             nullptr, nullptr, parts_mn, nullptr,
                             lds, lds + 128 * 64);
  } else {
    b -= nSt5;
    const int gm = m / 64;                    // 8
    const int bxi = b % gm, byi = (b / gm) % gm, bzi = b / (gm * gm);
    gemm_body<64, 64, false>(FT, FT, m, m, m, m / 4, bxi, byi, bzi,
                             nullptr, nullptr, parts_mm, nullptr,
                             lds, lds + 64 * 64);
  }
}

// ------- mega2: combine(St0)->Sb0  +  combine(FtF)->ghat + Frobenius ---------
// Last-arriving frob block (device-scope atomic; values order-independent)
// computes rn = 1/(||FtF||_F+eps) and writes scal0 = 0.8*lam*rn,
// scal1 = scal0^2 — rn is FOLDED into the doubling rowscales, so the
// unscaled ghat/ghat2 serve as the g-operands (algebraically identical).
__global__ void __launch_bounds__(256)
k_mega2(const s16* __restrict__ parts_mn, const s16* __restrict__ parts_mm,
        const float* __restrict__ lam, int m, int n,
        s16* __restrict__ Sb0, s16* __restrict__ ghat,
        float* __restrict__ partial, float* __restrict__ scal,
        unsigned int* __restrict__ counter)
{
  const size_t MN = (size_t)m * n;
  const int tid = threadIdx.x;
  int b = blockIdx.x;
  const int nComb = (int)(MN / 2048);         // 1024
  if (b < nComb) {
    const size_t i8 = ((size_t)b * 256 + tid) * 8;
    short8 a  = *(const short8*)(parts_mn + i8);
    short8 bb = *(const short8*)(parts_mn + MN + i8);
    short8 c  = *(const short8*)(parts_mn + 2 * MN + i8);
    short8 d  = *(const short8*)(parts_mn + 3 * MN + i8);
    short8 o;
    #pragma unroll
    for (int r = 0; r < 8; ++r)
      o[r] = f2bf((bf2f(a[r]) + bf2f(bb[r])) + (bf2f(c[r]) + bf2f(d[r])));
    *(short8*)(Sb0 + i8) = o;
    return;
  }
  const int row = b - nComb;                  // 0..m-1
  const size_t MM = (size_t)m * m;
  float ss = 0.f;
  for (int c = tid; c < m; c += 256) {
    const size_t idx = (size_t)row * m + c;
    const float v = (bf2f(parts_mm[idx]) + bf2f(parts_mm[MM + idx]))
                  + (bf2f(parts_mm[2 * MM + idx]) + bf2f(parts_mm[3 * MM + idx]));
    ghat[idx] = f2bf(v);
    ss += v * v;
  }
  __shared__ float red[256];
  __shared__ int lastFlag;
  red[tid] = ss; __syncthreads();
  for (int o = 128; o > 0; o >>= 1) {
    if (tid < o) red[tid] += red[tid + o];
    __syncthreads();
  }
  if (tid == 0) {
    partial[row] = red[0];
    __threadfence();                               // release partial[row]
    const unsigned int old = atomicAdd(counter, 1u);
    lastFlag = (old == (unsigned int)(m - 1));
  }
  __syncthreads();
  if (!lastFlag) return;
  __threadfence();                                 // acquire all partial[]
  float s = 0.f;
  for (int i = tid; i < m; i += 256) s += partial[i];
  red[tid] = s; __syncthreads();
  for (int o = 128; o > 0; o >>= 1) {
    if (tid < o) red[tid] += red[tid + o];
    __syncthreads();
  }
  const float rn = 1.0f / (sqrtf(red[0]) + 1e-12f);
  for (int j = tid; j < n; j += 256) {
    const float v = 0.8f * lam[j] * rn;
    scal[j] = v;
    scal[n + j] = v * v;
  }
}

// ------- mega3: doubling0 (St1 = St0 + rs0.(St0@ghat)) + squaring ghat2 ------
__global__ void __launch_bounds__(256, 2)
k_mega3(const s16* __restrict__ Sb0, const s16* __restrict__ ghat,
        const float* __restrict__ scal0,
        s16* __restrict__ Sb1, s16* __restrict__ ghat2, int m, int n)
{
  __shared__ alignas(16) s16 lds[128 * 64];   // 16 KB both paths
  int b = blockIdx.x;
  const int nD0 = (n / 64) * (m / 64);        // 512
  if (b < nD0) {
    const int bxi = b % (n / 64), byi = b / (n / 64);
    gemm_body<64, 64, true>(Sb0, ghat, n, m, m, m, bxi, byi, 0,
                            scal0, Sb0, Sb1, nullptr, lds, lds + 64 * 64);
  } else {
    b -= nD0;
    const int bxi = b % (m / 64), byi = b / (m / 64);
    gemm_body<64, 64, false>(ghat, ghat, m, m, m, m, bxi, byi, 0,
                             nullptr, nullptr, ghat2, nullptr, lds, lds + 64 * 64);
  }
}

// ------- combine (KS=4, bf16 slices) -> fp32 out -----------------------------
__global__ void __launch_bounds__(256)
k_combine4b(const s16* __restrict__ parts, size_t MN, float* __restrict__ Cf)
{
  const size_t i8 = ((size_t)blockIdx.x * 256 + threadIdx.x) * 8;
  if (i8 >= MN) return;
  short8 a = *(const short8*)(parts + i8);
  short8 b = *(const short8*)(parts + MN + i8);
  short8 c = *(const short8*)(parts + 2 * MN + i8);
  short8 d = *(const short8*)(parts + 3 * MN + i8);
  f32x4 lo, hi;
  #pragma unroll
  for (int r = 0; r < 4; ++r) {
    lo[r] = (bf2f(a[r]) + bf2f(b[r])) + (bf2f(c[r]) + bf2f(d[r]));
    hi[r] = (bf2f(a[r + 4]) + bf2f(b[r + 4])) + (bf2f(c[r + 4]) + bf2f(d[r + 4]));
  }
  *(f32x4*)(Cf + i8) = lo;
  *(f32x4*)(Cf + i8 + 4) = hi;
}

// ------- fused conversion: 128x128 tiles, 256B-run stores --------------------
__device__ __forceinline__ void cvt128(const float* __restrict__ in,
                                       s16* __restrict__ outp, s16* __restrict__ outt,
                                       int R, int C, int bx128, int by128,
                                       uint32_t (*t32)[65], int tid)
{
  const int bx = bx128 * 128, by = by128 * 128;
  const int u = tid & 15, v = tid >> 4;
  const int c8 = u * 8;
  #pragma unroll
  for (int rr = 0; rr < 8; ++rr) {
    const int r = rr * 16 + v;
    const float* src = in + (size_t)(by + r) * C + bx + c8;
    const f32x4 a = *(const f32x4*)src;
    const f32x4 b = *(const f32x4*)(src + 4);
    s16 e[8];
    e[0] = f2bf(a[0]); e[1] = f2bf(a[1]); e[2] = f2bf(a[2]); e[3] = f2bf(a[3]);
    e[4] = f2bf(b[0]); e[5] = f2bf(b[1]); e[6] = f2bf(b[2]); e[7] = f2bf(b[3]);
    if (outp) {
      short8 o;
      #pragma unroll
      for (int j = 0; j < 8; ++j) o[j] = e[j];
      *(short8*)(outp + (size_t)(by + r) * C + bx + c8) = o;
    }
    if (outt) {
      u32x4 w;
      #pragma unroll
      for (int j = 0; j < 4; ++j)
        w[j] = ((uint32_t)(uint16_t)e[2 * j]) | (((uint32_t)(uint16_t)e[2 * j + 1]) << 16);
      *(u32x4*)&t32[r][c8 >> 1] = w;
    }
  }
  if (outt) {
    __syncthreads();
    const int r8 = u * 8;
    #pragma unroll
    for (int p = 0; p < 8; ++p) {
      const int c  = p * 16 + v;
      const int cw = c >> 1;
      const int sh = (c & 1) * 16;
      short8 o;
      #pragma unroll
      for (int j = 0; j < 8; ++j)
        o[j] = (s16)(uint16_t)((t32[r8 + j][cw] >> sh) & 0xffffu);
      *(short8*)(outt + (size_t)(bx + c) * R + by + r8) = o;
    }
  }
}

__global__ void __launch_bounds__(256)
k_cvt_all(const float* __restrict__ Q, const float* __restrict__ X,
          const float* __restrict__ F,
          s16* __restrict__ Qbf, s16* __restrict__ QTbf,
          s16* __restrict__ Xbf, s16* __restrict__ FTbf,
          unsigned int* __restrict__ counter, int m, int n)
{
  __shared__ uint32_t t32[128][65];
  const int tid = threadIdx.x;
  int b = blockIdx.x;
  if (b == 0 && tid == 0) *counter = 0u;     // arm mega2's arrival counter
  const int qx = n / 128;
  const int mx = m / 128;
  const int nQ = qx * qx;
  const int nX = qx * mx;
  if (b < nQ) {
    cvt128(Q, Qbf, QTbf, n, n, b % qx, b / qx, t32, tid);
  } else if ((b -= nQ) < nX) {
    cvt128(X, Xbf, nullptr, m, n, b % qx, b / qx, t32, tid);
  } else {
    b -= nX;
    cvt128(F, nullptr, FTbf, m, m, b % mx, b / mx, t32, tid);
  }
}

// ---------------- driver ----------------
extern "C" void kernel_launch(void* const* d_in, const int* in_sizes, int n_in,
                              void* d_out, int out_size, void* d_ws, size_t ws_size,
                              hipStream_t stream)
{
  const float* X   = (const float*)d_in[0];   // (m, n)
  const float* F   = (const float*)d_in[1];   // (m, m)
  const float* Q   = (const float*)d_in[2];   // (n, n)
  const float* lam = (const float*)d_in[3];   // (n,)

  int m = 1;
  while ((long long)m * m < (long long)in_sizes[1]) ++m;   // 512
  const int n = in_sizes[0] / m;                           // 4096
  const size_t MN = (size_t)m * n;
  const size_t MM = (size_t)m * m;

  char* w = (char*)d_ws;
  auto take = [&](size_t bytes) -> void* {
    char* p = w;
    w += (bytes + 255) & ~(size_t)255;
    return (void*)p;
  };

  // ~96 MB; ws ~256 MB. Only alias: Splain = Sb0 (dead after mega3).
  s16*   Qbf   = (s16*)take((size_t)n * n * 2);
  s16*   QTbf  = (s16*)take((size_t)n * n * 2);
  s16*   Xbf   = (s16*)take(MN * 2);
  s16*   FTbf  = (s16*)take(MM * 2);
  s16*   ghat  = (s16*)take(MM * 2);             // bf16(FtF)   (unscaled)
  s16*   ghat2 = (s16*)take(MM * 2);             // bf16(FtF^2) (unscaled)
  float* scal  = (float*)take((size_t)2 * n * 4);
  float* part  = (float*)take((size_t)m * 4);
  unsigned int* counter = (unsigned int*)take(256);
  s16*   Sb0   = (s16*)take(MN * 2);
  s16*   Sb1   = (s16*)take(MN * 2);
  s16*   parts_mn = (s16*)take(4 * MN * 2);
  s16*   parts_mm = (s16*)take(4 * MM * 2);
  (void)ws_size; (void)n_in; (void)out_size;

  s16* Splain = Sb0;

  const dim3 blk(256);
  const int nCvt = (n / 128) * (n / 128) + (n / 128) * (m / 128)
                 + (m / 128) * (m / 128);

  // 1) conversions (Q dual, X, F^T) + counter reset
  k_cvt_all<<<dim3(nCvt), blk, 0, stream>>>(Q, X, F, Qbf, QTbf, Xbf, FTbf,
                                            counter, m, n);

  // 2) mega1: St0 = Q^T X^T (128x64, MAP, KS=4) + FtF = F^T F (64x64, KS=4)
  k_mega1<<<dim3((n / 128) * (m / 64) * 4 + (m / 64) * (m / 64) * 4),
            blk, 0, stream>>>(QTbf, Xbf, FTbf, m, n, parts_mn, parts_mm);

  // 3) mega2: combine->Sb0 + combine+frob->ghat; last block -> rn, scal0/1
  k_mega2<<<dim3((unsigned)(MN / 2048) + m), blk, 0, stream>>>(
      parts_mn, parts_mm, lam, m, n, Sb0, ghat, part, scal, counter);

  // 4) mega3: doubling0 -> Sb1  +  squaring ghat2 = ghat @ ghat (KS=1)
  k_mega3<<<dim3((n / 64) * (m / 64) + (m / 64) * (m / 64)), blk, 0, stream>>>(
      Sb0, ghat, scal, Sb1, ghat2, m, n);

  // 5) doubling1: St2 = St1 + rs1.(St1@ghat2); emit S plain via obf_t
  gemm_t<64, 64, true, 0><<<dim3(n / 64, m / 64, 1), blk, 0, stream>>>(
      Sb1, ghat2, n, m, m, m, 0, scal + n, Sb1, nullptr, Splain);

  // 6) st7: Z = S @ Q^T (64x128, MAP, KS=4) -> bf16 partials
  gemm_t<64, 128, false, 1><<<dim3((n / 128) * (m / 64) * 4), blk, 0, stream>>>(
      Splain, Qbf, m, n, n, n / 4, n / 128, nullptr, nullptr, parts_mn, nullptr);

  // 7) final combine -> d_out fp32
  k_combine4b<<<dim3((unsigned)(MN / 2048)), blk, 0, stream>>>(
      parts_mn, MN, (float*)d_out);
}

// Round 11
// 130.092 us; speedup vs baseline: 3.8737x; 1.0226x over previous
//
#include <hip/hip_runtime.h>
#include <stdint.h>

typedef short s16;
typedef __attribute__((ext_vector_type(8))) short short8;  // 8 bf16 (4 VGPRs)
typedef __attribute__((ext_vector_type(4))) float f32x4;

__device__ __forceinline__ s16 f2bf(float f) {
  union { float f; uint32_t u; } v; v.f = f;
  uint32_t u = v.u;
  uint32_t r = (u + 0x7fffu + ((u >> 16) & 1u)) >> 16;  // RNE
  return (s16)(uint16_t)r;
}
__device__ __forceinline__ float bf2f(s16 b) {
  union { uint32_t u; float f; } v; v.u = ((uint32_t)(uint16_t)b) << 16;
  return v.f;
}

#define GLOBAL_AS __attribute__((address_space(1)))
#define LDS_AS    __attribute__((address_space(3)))
__device__ __forceinline__ void gload_lds16(const void* g, void* l) {
  __builtin_amdgcn_global_load_lds((const GLOBAL_AS uint32_t*)g, (LDS_AS uint32_t*)l, 16, 0, 0);
}

// ---------------- GEMM body: C(MxN) = A(MxK,row) @ B, B given as BT(NxK,row) --
// PROVEN single-buffer 2-barrier K-loop, BK=64, XOR-swizzled LDS via
// pre-swizzled global source. Verbatim since round 3.
template<int BM_, int BN_, bool SX>
__device__ __forceinline__ void
gemm_body(const s16* __restrict__ A, const s16* __restrict__ BT,
          int M, int N, int K, int Kc, int bxi, int byi, int bzi,
          const float* __restrict__ rowscale,
          const s16* __restrict__ addend_bf,   // read-only; may equal A
          s16* __restrict__ obf_n, s16* __restrict__ obf_t,
          s16* lta, s16* ltb)
{
  constexpr int SWA = BM_ / 32;
  constexpr int SWB = BN_ / 32;
  constexpr int WM  = BM_ / 2;
  constexpr int WN  = BN_ / 2;
  constexpr int IM  = WM / 16;
  constexpr int JN  = WN / 16;

  const int tid  = threadIdx.x;
  const int lane = tid & 63;
  const int wave = tid >> 6;
  const int wr = wave >> 1, wc = wave & 1;
  const int bm0 = (SX ? bxi : byi) * BM_;
  const int bn0 = (SX ? byi : bxi) * BN_;
  const int k0  = bzi * Kc;

  f32x4 acc[IM][JN];
  #pragma unroll
  for (int i = 0; i < IM; ++i)
    #pragma unroll
    for (int j = 0; j < JN; ++j)
      #pragma unroll
      for (int r = 0; r < 4; ++r) acc[i][j][r] = 0.0f;

  const int lrow = lane >> 3;
  const int lke  = ((lane & 7) ^ lrow) * 8;
  const s16* Ab = A  + (size_t)(bm0 + wave * 8 + lrow) * K + k0 + lke;
  const s16* Bb = BT + (size_t)(bn0 + wave * 8 + lrow) * K + k0 + lke;

  const int fr = lane & 15;
  const int k8 = (lane >> 4) * 8;
  const int sw = (fr & 7) * 8;       // read-side XOR: row&7 == fr&7

  const int nt = Kc / 64;
  for (int t = 0; t < nt; ++t) {
    const int ko = t * 64;
    #pragma unroll
    for (int s = 0; s < SWA; ++s)
      gload_lds16(Ab + (size_t)s * 32 * K + ko, &lta[s * 2048 + wave * 512]);
    #pragma unroll
    for (int s = 0; s < SWB; ++s)
      gload_lds16(Bb + (size_t)s * 32 * K + ko, &ltb[s * 2048 + wave * 512]);
    __syncthreads();   // drains vmcnt(0): tile fully staged

    short8 af[2][IM], bfv[2][JN];
    #pragma unroll
    for (int kk = 0; kk < 2; ++kk) {
      #pragma unroll
      for (int i = 0; i < IM; ++i)
        af[kk][i] = *(const short8*)&lta[(wr * WM + i * 16 + fr) * 64 + ((kk * 32 + k8) ^ sw)];
      #pragma unroll
      for (int j = 0; j < JN; ++j)
        bfv[kk][j] = *(const short8*)&ltb[(wc * WN + j * 16 + fr) * 64 + ((kk * 32 + k8) ^ sw)];
    }
    #pragma unroll
    for (int kk = 0; kk < 2; ++kk)
      #pragma unroll
      for (int i = 0; i < IM; ++i)
        #pragma unroll
        for (int j = 0; j < JN; ++j)
          acc[i][j] = __builtin_amdgcn_mfma_f32_16x16x32_bf16(af[kk][i], bfv[kk][j], acc[i][j], 0, 0, 0);
    __syncthreads();   // all waves done reading before next tile overwrites
  }

  // epilogue — C/D layout: col = lane&15, row = (lane>>4)*4 + reg
  s16* on = obf_n ? obf_n + (size_t)bzi * M * N : nullptr;
  const int r0 = (lane >> 4) * 4;
  const int cl = lane & 15;
  #pragma unroll
  for (int i = 0; i < IM; ++i) {
    const int gm = bm0 + wr * WM + i * 16 + r0;
    #pragma unroll
    for (int j = 0; j < JN; ++j) {
      const int gn = bn0 + wc * WN + j * 16 + cl;
      #pragma unroll
      for (int r = 0; r < 4; ++r) {
        const size_t idx = (size_t)(gm + r) * N + gn;
        float v = acc[i][j][r];
        if (rowscale)  v *= rowscale[gm + r];
        if (addend_bf) v += bf2f(addend_bf[idx]);
        if (on)    on[idx] = f2bf(v);
        if (obf_t) obf_t[(size_t)gn * M + (gm + r)] = f2bf(v);
      }
    }
  }
}

// ------- standalone GEMM wrapper (MAP=1: XCD-aware 1D decode) ----------------
template<int BM_, int BN_, bool SX, int MAP>
__global__ void __launch_bounds__(256, 2)
gemm_t(const s16* __restrict__ A, const s16* __restrict__ BT,
       int M, int N, int K, int Kc, int gx,
       const float* __restrict__ rowscale,
       const s16* __restrict__ addend_bf,
       s16* __restrict__ obf_n, s16* __restrict__ obf_t)
{
  __shared__ alignas(16) s16 lds[BM_ * 64 + BN_ * 64];
  int bxi, byi, bzi;
  if (MAP == 1) {
    const int fid = blockIdx.x;
    const int c  = fid & 7;
    const int tt = fid >> 3;
    const int gxh = gx >> 1;
    bzi = c & 3;
    bxi = (c >> 2) * gxh + tt % gxh;
    byi = tt / gxh;
  } else {
    bxi = blockIdx.x; byi = blockIdx.y; bzi = blockIdx.z;
  }
  gemm_body<BM_, BN_, SX>(A, BT, M, N, K, Kc, bxi, byi, bzi,
                          rowscale, addend_bf, obf_n, obf_t, lds, lds + BM_ * 64);
}

// ------- mega1: st5 GEMM (St0 partials) + FtF GEMM (partials) ----------------
__global__ void __launch_bounds__(256, 2)
k_mega1(const s16* __restrict__ QT, const s16* __restrict__ Xb,
        const s16* __restrict__ FT, int m, int n,
        s16* __restrict__ parts_mn, s16* __restrict__ parts_mm)
{
  __shared__ alignas(16) s16 lds[192 * 64];   // 24.5 KB (max of both paths)
  int b = blockIdx.x;
  const int gx = n / 128;
  const int nSt5 = gx * (m / 64) * 4;         // 1024
  if (b < nSt5) {
    const int c = b & 7, tt = b >> 3, gxh = gx >> 1;
    const int bzi = c & 3, bxi = (c >> 2) * gxh + tt % gxh, byi = tt / gxh;
    gemm_body<128, 64, true>(QT, Xb, n, m, n, n / 4, bxi, byi, bzi,
                             nullptr, nullptr, parts_mn, nullptr,
                             lds, lds + 128 * 64);
  } else {
    b -= nSt5;
    const int gm = m / 64;                    // 8
    const int bxi = b % gm, byi = (b / gm) % gm, bzi = b / (gm * gm);
    gemm_body<64, 64, false>(FT, FT, m, m, m, m / 4, bxi, byi, bzi,
                             nullptr, nullptr, parts_mm, nullptr,
                             lds, lds + 64 * 64);
  }
}

// ------- mega2: combine(St0)->Sb0  +  combine(FtF)->ghat + Frobenius ---------
// Last-arriving frob block computes rn = 1/(||FtF||_F+eps) and folds it into
// the doubling rowscales scal0 = 0.8*lam*rn, scal1 = scal0^2.
__global__ void __launch_bounds__(256)
k_mega2(const s16* __restrict__ parts_mn, const s16* __restrict__ parts_mm,
        const float* __restrict__ lam, int m, int n,
        s16* __restrict__ Sb0, s16* __restrict__ ghat,
        float* __restrict__ partial, float* __restrict__ scal,
        unsigned int* __restrict__ counter)
{
  const size_t MN = (size_t)m * n;
  const int tid = threadIdx.x;
  int b = blockIdx.x;
  const int nComb = (int)(MN / 2048);         // 1024
  if (b < nComb) {
    const size_t i8 = ((size_t)b * 256 + tid) * 8;
    short8 a  = *(const short8*)(parts_mn + i8);
    short8 bb = *(const short8*)(parts_mn + MN + i8);
    short8 c  = *(const short8*)(parts_mn + 2 * MN + i8);
    short8 d  = *(const short8*)(parts_mn + 3 * MN + i8);
    short8 o;
    #pragma unroll
    for (int r = 0; r < 8; ++r)
      o[r] = f2bf((bf2f(a[r]) + bf2f(bb[r])) + (bf2f(c[r]) + bf2f(d[r])));
    *(short8*)(Sb0 + i8) = o;
    return;
  }
  const int row = b - nComb;                  // 0..m-1
  const size_t MM = (size_t)m * m;
  float ss = 0.f;
  for (int c = tid; c < m; c += 256) {
    const size_t idx = (size_t)row * m + c;
    const float v = (bf2f(parts_mm[idx]) + bf2f(parts_mm[MM + idx]))
                  + (bf2f(parts_mm[2 * MM + idx]) + bf2f(parts_mm[3 * MM + idx]));
    ghat[idx] = f2bf(v);
    ss += v * v;
  }
  __shared__ float red[256];
  __shared__ int lastFlag;
  red[tid] = ss; __syncthreads();
  for (int o = 128; o > 0; o >>= 1) {
    if (tid < o) red[tid] += red[tid + o];
    __syncthreads();
  }
  if (tid == 0) {
    partial[row] = red[0];
    __threadfence();                               // release partial[row]
    const unsigned int old = atomicAdd(counter, 1u);
    lastFlag = (old == (unsigned int)(m - 1));
  }
  __syncthreads();
  if (!lastFlag) return;
  __threadfence();                                 // acquire all partial[]
  float s = 0.f;
  for (int i = tid; i < m; i += 256) s += partial[i];
  red[tid] = s; __syncthreads();
  for (int o = 128; o > 0; o >>= 1) {
    if (tid < o) red[tid] += red[tid + o];
    __syncthreads();
  }
  const float rn = 1.0f / (sqrtf(red[0]) + 1e-12f);
  for (int j = tid; j < n; j += 256) {
    const float v = 0.8f * lam[j] * rn;
    scal[j] = v;
    scal[n + j] = v * v;
  }
}

// ------- mega3: doubling0 (St1 = St0 + rs0.(St0@ghat)) + squaring ghat2 ------
__global__ void __launch_bounds__(256, 2)
k_mega3(const s16* __restrict__ Sb0, const s16* __restrict__ ghat,
        const float* __restrict__ scal0,
        s16* __restrict__ Sb1, s16* __restrict__ ghat2, int m, int n)
{
  __shared__ alignas(16) s16 lds[128 * 64];   // 16 KB both paths
  int b = blockIdx.x;
  const int nD0 = (n / 64) * (m / 64);        // 512
  if (b < nD0) {
    const int bxi = b % (n / 64), byi = b / (n / 64);
    gemm_body<64, 64, true>(Sb0, ghat, n, m, m, m, bxi, byi, 0,
                            scal0, Sb0, Sb1, nullptr, lds, lds + 64 * 64);
  } else {
    b -= nD0;
    const int bxi = b % (m / 64), byi = b / (m / 64);
    gemm_body<64, 64, false>(ghat, ghat, m, m, m, m, bxi, byi, 0,
                             nullptr, nullptr, ghat2, nullptr, lds, lds + 64 * 64);
  }
}

// ------- combine (KS=4, bf16 slices) -> fp32 out -----------------------------
__global__ void __launch_bounds__(256)
k_combine4b(const s16* __restrict__ parts, size_t MN, float* __restrict__ Cf)
{
  const size_t i8 = ((size_t)blockIdx.x * 256 + threadIdx.x) * 8;
  if (i8 >= MN) return;
  short8 a = *(const short8*)(parts + i8);
  short8 b = *(const short8*)(parts + MN + i8);
  short8 c = *(const short8*)(parts + 2 * MN + i8);
  short8 d = *(const short8*)(parts + 3 * MN + i8);
  f32x4 lo, hi;
  #pragma unroll
  for (int r = 0; r < 4; ++r) {
    lo[r] = (bf2f(a[r]) + bf2f(b[r])) + (bf2f(c[r]) + bf2f(d[r]));
    hi[r] = (bf2f(a[r + 4]) + bf2f(b[r + 4])) + (bf2f(c[r + 4]) + bf2f(d[r + 4]));
  }
  *(f32x4*)(Cf + i8) = lo;
  *(f32x4*)(Cf + i8 + 4) = hi;
}

// ------- conversion ----------------------------------------------------------
// Dual-output (plain + transposed) tiles now run as two 128r x 64c halves over
// a 16.9 KB LDS buffer (u32 [128][33], b32 stores, XOR-4 skew) -> 8 blocks/CU
// (vs 4 at the old 33 KB tile) to hide store latency with TLP. Phase-2 read
// conflict drops 4-way -> ~2-way (free, m136). Plain-only (X) keeps the
// full-width streaming path (no LDS).
__device__ __forceinline__ void cvt_dual_h(const float* __restrict__ in,
                                           s16* __restrict__ outp,
                                           s16* __restrict__ outt,
                                           int R, int C, int bx128, int by128,
                                           uint32_t (*t32)[33], int tid)
{
  const int bx = bx128 * 128, by = by128 * 128;
  const int u  = tid & 7;          // col-group in half: 8 floats each
  const int vr = tid >> 3;         // 0..31 row within sweep
  const int uu = tid & 15;         // phase-2: row-group (8 rows)
  const int vv = tid >> 4;         // phase-2: 0..15
  const int k4r = (uu >> 2) << 2;  // phase-2 XOR: ((r8+j)>>5)<<2 == (uu>>2)<<2
  #pragma unroll
  for (int h = 0; h < 2; ++h) {
    if (h) __syncthreads();        // reuse LDS across halves
    const int c8 = h * 64 + u * 8;
    #pragma unroll
    for (int rr = 0; rr < 4; ++rr) {
      const int r = rr * 32 + vr;
      const float* src = in + (size_t)(by + r) * C + bx + c8;
      const f32x4 a = *(const f32x4*)src;
      const f32x4 b = *(const f32x4*)(src + 4);
      s16 e[8];
      e[0] = f2bf(a[0]); e[1] = f2bf(a[1]); e[2] = f2bf(a[2]); e[3] = f2bf(a[3]);
      e[4] = f2bf(b[0]); e[5] = f2bf(b[1]); e[6] = f2bf(b[2]); e[7] = f2bf(b[3]);
      if (outp) {
        short8 o;
        #pragma unroll
        for (int j = 0; j < 8; ++j) o[j] = e[j];
        *(short8*)(outp + (size_t)(by + r) * C + bx + c8) = o;
      }
      const int k4 = rr << 2;      // (r>>5)<<2 since r = rr*32 + vr, vr<32
      #pragma unroll
      for (int jj = 0; jj < 4; ++jj)
        t32[r][(u * 4 + jj) ^ k4] =
            ((uint32_t)(uint16_t)e[2 * jj]) | (((uint32_t)(uint16_t)e[2 * jj + 1]) << 16);
    }
    __syncthreads();
    const int r8 = uu * 8;
    #pragma unroll
    for (int p = 0; p < 4; ++p) {
      const int cl = p * 16 + vv;          // 0..63 within half
      const int c  = h * 64 + cl;
      const int w  = cl >> 1;
      const int sh = (cl & 1) * 16;
      short8 o;
      #pragma unroll
      for (int j = 0; j < 8; ++j)
        o[j] = (s16)(uint16_t)((t32[r8 + j][w ^ k4r] >> sh) & 0xffffu);
      *(short8*)(outt + (size_t)(bx + c) * R + by + r8) = o;
    }
  }
}

__device__ __forceinline__ void cvt_plain(const float* __restrict__ in,
                                          s16* __restrict__ outp,
                                          int C, int bx128, int by128, int tid)
{
  const int bx = bx128 * 128, by = by128 * 128;
  const int u = tid & 15, v = tid >> 4;
  const int c8 = u * 8;
  #pragma unroll
  for (int rr = 0; rr < 8; ++rr) {
    const int r = rr * 16 + v;
    const float* src = in + (size_t)(by + r) * C + bx + c8;
    const f32x4 a = *(const f32x4*)src;
    const f32x4 b = *(const f32x4*)(src + 4);
    short8 o;
    o[0] = f2bf(a[0]); o[1] = f2bf(a[1]); o[2] = f2bf(a[2]); o[3] = f2bf(a[3]);
    o[4] = f2bf(b[0]); o[5] = f2bf(b[1]); o[6] = f2bf(b[2]); o[7] = f2bf(b[3]);
    *(short8*)(outp + (size_t)(by + r) * C + bx + c8) = o;
  }
}

__global__ void __launch_bounds__(256)
k_cvt_all(const float* __restrict__ Q, const float* __restrict__ X,
          const float* __restrict__ F,
          s16* __restrict__ Qbf, s16* __restrict__ QTbf,
          s16* __restrict__ Xbf, s16* __restrict__ FTbf,
          unsigned int* __restrict__ counter, int m, int n)
{
  __shared__ uint32_t t32[128][33];          // 16.9 KB -> 8 blocks/CU
  const int tid = threadIdx.x;
  int b = blockIdx.x;
  if (b == 0 && tid == 0) *counter = 0u;     // arm mega2's arrival counter
  const int qx = n / 128;
  const int mx = m / 128;
  const int nQ = qx * qx;
  const int nX = qx * mx;
  if (b < nQ) {
    cvt_dual_h(Q, Qbf, QTbf, n, n, b % qx, b / qx, t32, tid);
  } else if ((b -= nQ) < nX) {
    cvt_plain(X, Xbf, n, b % qx, b / qx, tid);
  } else {
    b -= nX;
    cvt_dual_h(F, nullptr, FTbf, m, m, b % mx, b / mx, t32, tid);
  }
}

// ---------------- driver ----------------
extern "C" void kernel_launch(void* const* d_in, const int* in_sizes, int n_in,
                              void* d_out, int out_size, void* d_ws, size_t ws_size,
                              hipStream_t stream)
{
  const float* X   = (const float*)d_in[0];   // (m, n)
  const float* F   = (const float*)d_in[1];   // (m, m)
  const float* Q   = (const float*)d_in[2];   // (n, n)
  const float* lam = (const float*)d_in[3];   // (n,)

  int m = 1;
  while ((long long)m * m < (long long)in_sizes[1]) ++m;   // 512
  const int n = in_sizes[0] / m;                           // 4096
  const size_t MN = (size_t)m * n;
  const size_t MM = (size_t)m * m;

  char* w = (char*)d_ws;
  auto take = [&](size_t bytes) -> void* {
    char* p = w;
    w += (bytes + 255) & ~(size_t)255;
    return (void*)p;
  };

  // ~96 MB; ws ~256 MB. Only alias: Splain = Sb0 (dead after mega3).
  s16*   Qbf   = (s16*)take((size_t)n * n * 2);
  s16*   QTbf  = (s16*)take((size_t)n * n * 2);
  s16*   Xbf   = (s16*)take(MN * 2);
  s16*   FTbf  = (s16*)take(MM * 2);
  s16*   ghat  = (s16*)take(MM * 2);             // bf16(FtF)   (unscaled)
  s16*   ghat2 = (s16*)take(MM * 2);             // bf16(FtF^2) (unscaled)
  float* scal  = (float*)take((size_t)2 * n * 4);
  float* part  = (float*)take((size_t)m * 4);
  unsigned int* counter = (unsigned int*)take(256);
  s16*   Sb0   = (s16*)take(MN * 2);
  s16*   Sb1   = (s16*)take(MN * 2);
  s16*   parts_mn = (s16*)take(4 * MN * 2);
  s16*   parts_mm = (s16*)take(4 * MM * 2);
  (void)ws_size; (void)n_in; (void)out_size;

  s16* Splain = Sb0;

  const dim3 blk(256);
  const int nCvt = (n / 128) * (n / 128) + (n / 128) * (m / 128)
                 + (m / 128) * (m / 128);

  // 1) conversions (Q dual, X, F^T) + counter reset
  k_cvt_all<<<dim3(nCvt), blk, 0, stream>>>(Q, X, F, Qbf, QTbf, Xbf, FTbf,
                                            counter, m, n);

  // 2) mega1: St0 = Q^T X^T (128x64, MAP, KS=4) + FtF = F^T F (64x64, KS=4)
  k_mega1<<<dim3((n / 128) * (m / 64) * 4 + (m / 64) * (m / 64) * 4),
            blk, 0, stream>>>(QTbf, Xbf, FTbf, m, n, parts_mn, parts_mm);

  // 3) mega2: combine->Sb0 + combine+frob->ghat; last block -> rn, scal0/1
  k_mega2<<<dim3((unsigned)(MN / 2048) + m), blk, 0, stream>>>(
      parts_mn, parts_mm, lam, m, n, Sb0, ghat, part, scal, counter);

  // 4) mega3: doubling0 -> Sb1  +  squaring ghat2 = ghat @ ghat (KS=1)
  k_mega3<<<dim3((n / 64) * (m / 64) + (m / 64) * (m / 64)), blk, 0, stream>>>(
      Sb0, ghat, scal, Sb1, ghat2, m, n);

  // 5) doubling1: St2 = St1 + rs1.(St1@ghat2); emit S plain via obf_t
  gemm_t<64, 64, true, 0><<<dim3(n / 64, m / 64, 1), blk, 0, stream>>>(
      Sb1, ghat2, n, m, m, m, 0, scal + n, Sb1, nullptr, Splain);

  // 6) st7: Z = S @ Q^T (64x128, MAP, KS=4) -> bf16 partials
  gemm_t<64, 128, false, 1><<<dim3((n / 128) * (m / 64) * 4), blk, 0, stream>>>(
      Splain, Qbf, m, n, n, n / 4, n / 128, nullptr, nullptr, parts_mn, nullptr);

  // 7) final combine -> d_out fp32
  k_combine4b<<<dim3((unsigned)(MN / 2048)), blk, 0, stream>>>(
      parts_mn, MN, (float*)d_out);
}